// Round 1
// baseline (210.512 us; speedup 1.0000x reference)
//
#include <hip/hip_runtime.h>
#include <stdint.h>

// MultiHeadAttention: B=2, S=2048, H=16, Dh=64, Dm=1024
// Pipeline: pack(fp32->bf16) -> W transpose -> QKV GEMM (MFMA) -> flash attn -> out GEMM
#define DM 1024
#define HNUM 16
#define DH 64
#define BB 2
#define SSEQ 2048
#define MTOT (BB*SSEQ) // 4096

typedef unsigned short ushort_t;
typedef __attribute__((ext_vector_type(8))) short bf16x8;
typedef __attribute__((ext_vector_type(4))) float f32x4;

// ---- bf16 helpers (bit-level, no hip_bf16 dependency) ----
__device__ __forceinline__ ushort_t f2bf(float f) {
  unsigned u = __builtin_bit_cast(unsigned, f);
  u += 0x7FFFu + ((u >> 16) & 1u);  // RNE
  return (ushort_t)(u >> 16);
}
__device__ __forceinline__ float bf2f(ushort_t h) {
  return __builtin_bit_cast(float, (unsigned)h << 16);
}

// ---- async global->LDS, 16B per lane; dest = wave-uniform base + lane*16 ----
typedef const __attribute__((address_space(1))) unsigned int* gas_ptr;
typedef __attribute__((address_space(3))) unsigned int* las_ptr;
__device__ __forceinline__ void gload_lds16(const void* g, void* l) {
  __builtin_amdgcn_global_load_lds((gas_ptr)(uintptr_t)g, (las_ptr)(uintptr_t)l, 16, 0, 0);
}

// ---- fp32 -> bf16 bulk convert (8 elems/thread) ----
__global__ void cvt_f32_bf16(const float* __restrict__ src, ushort_t* __restrict__ dst, int n8) {
  int idx = blockIdx.x * 256 + threadIdx.x;
  if (idx >= n8) return;
  const float4* s4 = (const float4*)src;
  float4 a = s4[idx * 2], c = s4[idx * 2 + 1];
  union { ushort_t h[8]; uint4 u; } o;
  o.h[0] = f2bf(a.x); o.h[1] = f2bf(a.y); o.h[2] = f2bf(a.z); o.h[3] = f2bf(a.w);
  o.h[4] = f2bf(c.x); o.h[5] = f2bf(c.y); o.h[6] = f2bf(c.z); o.h[7] = f2bf(c.w);
  ((uint4*)dst)[idx] = o.u;
}

// ---- transpose+convert: src fp32 [G][R][C] -> dst bf16 [G][C][R] ----
__global__ void transpose_cvt(const float* __restrict__ src, ushort_t* __restrict__ dst, int R, int C) {
  __shared__ ushort_t T[64][65];
  const int g = blockIdx.z;
  const int r0 = blockIdx.y * 64, c0 = blockIdx.x * 64;
  src += (size_t)g * R * C;
  dst += (size_t)g * R * C;
  const int tid = threadIdx.x;
  #pragma unroll
  for (int i = 0; i < 16; ++i) {
    int idx = i * 256 + tid;
    int r = idx >> 6, c = idx & 63;
    T[r][c] = f2bf(src[(size_t)(r0 + r) * C + c0 + c]);
  }
  __syncthreads();
  #pragma unroll
  for (int i = 0; i < 16; ++i) {
    int idx = i * 256 + tid;
    int cc = idx >> 6, rr = idx & 63;
    dst[(size_t)(c0 + cc) * R + r0 + rr] = T[rr][cc];
  }
}

// ---- shared 128x128-tile GEMM mainloop: C[128,128] = A[128rows,K=1024] * Bm^T, Bm is [n][k] ----
// LDS layout [row][64] bf16 with XOR swizzle: elem col ^= (row&7)*8 (byte ^= (row&7)<<4)
__device__ __forceinline__ void gemm_mainloop_128(const ushort_t* __restrict__ A,
                                                  const ushort_t* __restrict__ Bm,
                                                  f32x4 (&acc)[4][4], int m0, int n0, int l, int w) {
  __shared__ ushort_t As[128 * 64];
  __shared__ ushort_t Bs[128 * 64];
  const int wr = w >> 1, wc = w & 1;
  for (int ks = 0; ks < 16; ++ks) {
    const int k0 = ks * 64;
    #pragma unroll
    for (int it = 0; it < 4; ++it) {
      const int chunk = it * 4 + w;
      const int row = chunk * 8 + (l >> 3);
      const int kc = ((l & 7) * 8) ^ ((row & 7) * 8);  // pre-swizzled source
      gload_lds16(A + (size_t)(m0 + row) * 1024 + k0 + kc, (char*)As + chunk * 1024);
      gload_lds16(Bm + (size_t)(n0 + row) * 1024 + k0 + kc, (char*)Bs + chunk * 1024);
    }
    __syncthreads();
    #pragma unroll
    for (int kk = 0; kk < 2; ++kk) {
      bf16x8 af[4], bfr[4];
      #pragma unroll
      for (int mi = 0; mi < 4; ++mi) {
        const int row = wr * 64 + mi * 16 + (l & 15);
        const int kc = (kk * 32 + (l >> 4) * 8) ^ ((row & 7) * 8);
        af[mi] = *(const bf16x8*)(As + row * 64 + kc);
      }
      #pragma unroll
      for (int ni = 0; ni < 4; ++ni) {
        const int row = wc * 64 + ni * 16 + (l & 15);
        const int kc = (kk * 32 + (l >> 4) * 8) ^ ((row & 7) * 8);
        bfr[ni] = *(const bf16x8*)(Bs + row * 64 + kc);
      }
      #pragma unroll
      for (int mi = 0; mi < 4; ++mi)
        #pragma unroll
        for (int ni = 0; ni < 4; ++ni)
          acc[mi][ni] = __builtin_amdgcn_mfma_f32_16x16x32_bf16(af[mi], bfr[ni], acc[mi][ni], 0, 0, 0);
    }
    __syncthreads();
  }
}

// ---- QKV projection: z=0 Q, z=1 K (layout [b][h][s][e]), z=2 V (transposed [b][h][e][s]) ----
__global__ __launch_bounds__(256, 2) void qkv_gemm(
    const ushort_t* __restrict__ qb, const ushort_t* __restrict__ kb, const ushort_t* __restrict__ vb,
    const ushort_t* __restrict__ Wtq, const ushort_t* __restrict__ Wtk, const ushort_t* __restrict__ Wtv,
    const float* __restrict__ bq, const float* __restrict__ bk, const float* __restrict__ bv,
    ushort_t* __restrict__ Qo, ushort_t* __restrict__ Ko, ushort_t* __restrict__ Vto) {
  const int z = blockIdx.z;
  const ushort_t* A  = z == 0 ? qb : (z == 1 ? kb : vb);
  const ushort_t* Bm = z == 0 ? Wtq : (z == 1 ? Wtk : Wtv);
  const float* bias  = z == 0 ? bq : (z == 1 ? bk : bv);
  ushort_t* out      = z == 0 ? Qo : (z == 1 ? Ko : Vto);
  const int m0 = blockIdx.x * 128, n0 = blockIdx.y * 128;
  const int tid = threadIdx.x, l = tid & 63, w = tid >> 6;
  f32x4 acc[4][4] = {};
  gemm_mainloop_128(A, Bm, acc, m0, n0, l, w);
  const int wr = w >> 1, wc = w & 1;
  #pragma unroll
  for (int mi = 0; mi < 4; ++mi) {
    #pragma unroll
    for (int ni = 0; ni < 4; ++ni) {
      const int n = n0 + wc * 64 + ni * 16 + (l & 15);
      const float bb = bias[n];
      const int mbase = m0 + wr * 64 + mi * 16 + ((l >> 4) << 2);
      if (z < 2) {
        #pragma unroll
        for (int i = 0; i < 4; ++i) {
          const int m = mbase + i;
          const size_t o = (((size_t)((m >> 11) * 16 + (n >> 6))) * 2048 + (m & 2047)) * 64 + (n & 63);
          out[o] = f2bf(acc[mi][ni][i] + bb);
        }
      } else {
        union { ushort_t h[4]; uint2 u2; } pk;
        #pragma unroll
        for (int i = 0; i < 4; ++i) pk.h[i] = f2bf(acc[mi][ni][i] + bb);
        const size_t o = (((size_t)((mbase >> 11) * 16 + (n >> 6))) * 64 + (n & 63)) * 2048 + (mbase & 2047);
        *(uint2*)(out + o) = pk.u2;
      }
    }
  }
}

// ---- output projection: d_out fp32 [4096][1024] ----
__global__ __launch_bounds__(256, 2) void out_gemm(const ushort_t* __restrict__ A,
                                                   const ushort_t* __restrict__ Bm,
                                                   const float* __restrict__ bias,
                                                   float* __restrict__ out) {
  const int m0 = blockIdx.x * 128, n0 = blockIdx.y * 128;
  const int tid = threadIdx.x, l = tid & 63, w = tid >> 6;
  f32x4 acc[4][4] = {};
  gemm_mainloop_128(A, Bm, acc, m0, n0, l, w);
  const int wr = w >> 1, wc = w & 1;
  #pragma unroll
  for (int mi = 0; mi < 4; ++mi) {
    #pragma unroll
    for (int ni = 0; ni < 4; ++ni) {
      const int n = n0 + wc * 64 + ni * 16 + (l & 15);
      const float bb = bias[n];
      const int mbase = m0 + wr * 64 + mi * 16 + ((l >> 4) << 2);
      #pragma unroll
      for (int i = 0; i < 4; ++i)
        out[(size_t)(mbase + i) * 1024 + n] = acc[mi][ni][i] + bb;
    }
  }
}

// ---- flash attention: block = 128 q-rows x one (b,h); 4 waves x 32 rows; KVBLK=64 ----
__global__ __launch_bounds__(256, 2) void flash_attn(const ushort_t* __restrict__ Q,
                                                     const ushort_t* __restrict__ K,
                                                     const ushort_t* __restrict__ Vt,
                                                     const ushort_t* __restrict__ maskb,
                                                     ushort_t* __restrict__ concat) {
  const int bh = blockIdx.y, b = bh >> 4, h = bh & 15;
  const int s0 = blockIdx.x * 128;
  const int tid = threadIdx.x, l = tid & 63, w = tid >> 6;
  __shared__ ushort_t Ks[64 * 64];
  __shared__ ushort_t Vs[64 * 64];
  __shared__ ushort_t Pl[4 * 32 * 64];
  const ushort_t* Qb = Q + (size_t)bh * 2048 * 64;
  const ushort_t* Kb = K + (size_t)bh * 2048 * 64;
  const ushort_t* Vb = Vt + (size_t)bh * 64 * 2048;
  const int qrow_base = s0 + w * 32;

  // Q fragments held in registers for the whole kernel
  bf16x8 aq[2][2];
  #pragma unroll
  for (int mi = 0; mi < 2; ++mi)
    #pragma unroll
    for (int kq = 0; kq < 2; ++kq)
      aq[mi][kq] = *(const bf16x8*)(Qb + (size_t)(qrow_base + mi * 16 + (l & 15)) * 64 + kq * 32 + (l >> 4) * 8);

  float m_run[2][4], l_run[2][4];
  f32x4 acc_o[2][4] = {};
  #pragma unroll
  for (int mi = 0; mi < 2; ++mi)
    #pragma unroll
    for (int i = 0; i < 4; ++i) { m_run[mi][i] = -1e30f; l_run[mi][i] = 0.f; }
  const float scale = 0.125f;

  for (int t0 = 0; t0 < 2048; t0 += 64) {
    // stage K tile [t][e] and V^T tile [e][t], both 64x64 bf16, XOR-swizzled source
    #pragma unroll
    for (int half = 0; half < 2; ++half) {
      const int c = half * 4 + w;
      const int r1 = c * 8 + (l >> 3);
      const int cc = ((l & 7) * 8) ^ ((r1 & 7) * 8);
      gload_lds16(Kb + (size_t)(t0 + r1) * 64 + cc, (char*)Ks + c * 1024);
      gload_lds16(Vb + (size_t)r1 * 2048 + t0 + cc, (char*)Vs + c * 1024);
    }
    __syncthreads();

    // QK^T for this wave's 32 rows x 64 cols
    f32x4 sc[2][4] = {};
    #pragma unroll
    for (int kq = 0; kq < 2; ++kq) {
      bf16x8 bk4[4];
      #pragma unroll
      for (int nj = 0; nj < 4; ++nj) {
        const int row = nj * 16 + (l & 15);
        const int kc = (kq * 32 + (l >> 4) * 8) ^ ((row & 7) * 8);
        bk4[nj] = *(const bf16x8*)(Ks + row * 64 + kc);
      }
      #pragma unroll
      for (int mi = 0; mi < 2; ++mi)
        #pragma unroll
        for (int nj = 0; nj < 4; ++nj)
          sc[mi][nj] = __builtin_amdgcn_mfma_f32_16x16x32_bf16(aq[mi][kq], bk4[nj], sc[mi][nj], 0, 0, 0);
    }

    // scale * mask, tile row-max
    float tmax[2][4];
    #pragma unroll
    for (int mi = 0; mi < 2; ++mi)
      #pragma unroll
      for (int i = 0; i < 4; ++i) tmax[mi][i] = -1e30f;
    #pragma unroll
    for (int mi = 0; mi < 2; ++mi) {
      #pragma unroll
      for (int nj = 0; nj < 4; ++nj) {
        const int tcol = t0 + nj * 16 + (l & 15);
        #pragma unroll
        for (int i = 0; i < 4; ++i) {
          const int srow = qrow_base + mi * 16 + ((l >> 4) << 2) + i;
          const float mv = bf2f(maskb[(size_t)srow * 2048 + tcol]);
          const float v2 = sc[mi][nj][i] * scale * mv;
          sc[mi][nj][i] = v2;
          tmax[mi][i] = fmaxf(tmax[mi][i], v2);
        }
      }
    }
    // reduce row-max across the 16 lanes holding each row; online rescale
    #pragma unroll
    for (int mi = 0; mi < 2; ++mi)
      #pragma unroll
      for (int i = 0; i < 4; ++i) {
        float v2 = tmax[mi][i];
        v2 = fmaxf(v2, __shfl_xor(v2, 1));
        v2 = fmaxf(v2, __shfl_xor(v2, 2));
        v2 = fmaxf(v2, __shfl_xor(v2, 4));
        v2 = fmaxf(v2, __shfl_xor(v2, 8));
        const float mnew = fmaxf(m_run[mi][i], v2);
        const float rf = __expf(m_run[mi][i] - mnew);
        m_run[mi][i] = mnew;
        l_run[mi][i] *= rf;
        #pragma unroll
        for (int ne = 0; ne < 4; ++ne) acc_o[mi][ne][i] *= rf;
      }

    // P = exp(s - m), write to per-wave swizzled LDS, accumulate row sums
    #pragma unroll
    for (int mi = 0; mi < 2; ++mi) {
      float psum[4] = {0.f, 0.f, 0.f, 0.f};
      #pragma unroll
      for (int nj = 0; nj < 4; ++nj) {
        #pragma unroll
        for (int i = 0; i < 4; ++i) {
          const float p = __expf(sc[mi][nj][i] - m_run[mi][i]);
          psum[i] += p;
          const int r = mi * 16 + ((l >> 4) << 2) + i;
          const int cb = ((nj * 16 + (l & 15)) * 2) ^ ((r & 7) << 4);
          *(ushort_t*)((char*)Pl + w * 4096 + r * 128 + cb) = f2bf(p);
        }
      }
      #pragma unroll
      for (int i = 0; i < 4; ++i) {
        float s = psum[i];
        s += __shfl_xor(s, 1); s += __shfl_xor(s, 2);
        s += __shfl_xor(s, 4); s += __shfl_xor(s, 8);
        l_run[mi][i] += s;
      }
    }

    // PV: acc_o += P * V   (V^T rows are MFMA-B k-contiguous)
    #pragma unroll
    for (int kt = 0; kt < 2; ++kt) {
      bf16x8 ap[2], bv4[4];
      #pragma unroll
      for (int mi = 0; mi < 2; ++mi) {
        const int r = mi * 16 + (l & 15);
        const int cb = ((kt * 32 + (l >> 4) * 8) * 2) ^ ((r & 7) << 4);
        ap[mi] = *(const bf16x8*)((char*)Pl + w * 4096 + r * 128 + cb);
      }
      #pragma unroll
      for (int ne = 0; ne < 4; ++ne) {
        const int row = ne * 16 + (l & 15);
        const int kc = (kt * 32 + (l >> 4) * 8) ^ ((row & 7) * 8);
        bv4[ne] = *(const bf16x8*)(Vs + row * 64 + kc);
      }
      #pragma unroll
      for (int mi = 0; mi < 2; ++mi)
        #pragma unroll
        for (int ne = 0; ne < 4; ++ne)
          acc_o[mi][ne] = __builtin_amdgcn_mfma_f32_16x16x32_bf16(ap[mi], bv4[ne], acc_o[mi][ne], 0, 0, 0);
    }
    __syncthreads();
  }

  // normalize and write concat [b][s][h*64+e] (bf16)
  #pragma unroll
  for (int mi = 0; mi < 2; ++mi)
    #pragma unroll
    for (int ne = 0; ne < 4; ++ne) {
      const int e = ne * 16 + (l & 15);
      #pragma unroll
      for (int i = 0; i < 4; ++i) {
        const int srow = qrow_base + mi * 16 + ((l >> 4) << 2) + i;
        const float ov = acc_o[mi][ne][i] / l_run[mi][i];
        concat[((size_t)(b * 2048 + srow)) * 1024 + h * 64 + e] = f2bf(ov);
      }
    }
}

extern "C" void kernel_launch(void* const* d_in, const int* in_sizes, int n_in,
                              void* d_out, int out_size, void* d_ws, size_t ws_size,
                              hipStream_t stream) {
  const float* q    = (const float*)d_in[0];
  const float* k    = (const float*)d_in[1];
  const float* v    = (const float*)d_in[2];
  const float* mask = (const float*)d_in[3];
  const float* Wq   = (const float*)d_in[4];
  const float* bq   = (const float*)d_in[5];
  const float* Wk   = (const float*)d_in[6];
  const float* bk   = (const float*)d_in[7];
  const float* Wv   = (const float*)d_in[8];
  const float* bv   = (const float*)d_in[9];
  const float* Wo   = (const float*)d_in[10];
  const float* bo   = (const float*)d_in[11];

  const size_t SZ8M = (size_t)4096 * 1024 * 2;   // 8 MiB buffers (bf16)
  const size_t SZ2M = (size_t)1024 * 1024 * 2;   // 2 MiB weight buffers
  if (ws_size < 7 * SZ8M + 4 * SZ2M) return;     // need 64 MiB scratch

  char* p = (char*)d_ws;
  ushort_t* qb    = (ushort_t*)p; p += SZ8M;     // also reused as `concat` after qkv_gemm
  ushort_t* kb    = (ushort_t*)p; p += SZ8M;
  ushort_t* vb    = (ushort_t*)p; p += SZ8M;
  ushort_t* maskb = (ushort_t*)p; p += SZ8M;
  ushort_t* Qo    = (ushort_t*)p; p += SZ8M;
  ushort_t* Ko    = (ushort_t*)p; p += SZ8M;
  ushort_t* Vto   = (ushort_t*)p; p += SZ8M;
  ushort_t* Wtq   = (ushort_t*)p; p += SZ2M;
  ushort_t* Wtk   = (ushort_t*)p; p += SZ2M;
  ushort_t* Wtv   = (ushort_t*)p; p += SZ2M;
  ushort_t* Wot   = (ushort_t*)p; p += SZ2M;
  ushort_t* concat = qb;  // qb is dead after qkv_gemm; flash writes it before out_gemm reads

  const int n8 = (4096 * 1024) / 8;  // 524288
  cvt_f32_bf16<<<dim3(2048), dim3(256), 0, stream>>>(q, qb, n8);
  cvt_f32_bf16<<<dim3(2048), dim3(256), 0, stream>>>(k, kb, n8);
  cvt_f32_bf16<<<dim3(2048), dim3(256), 0, stream>>>(v, vb, n8);
  cvt_f32_bf16<<<dim3(2048), dim3(256), 0, stream>>>(mask, maskb, n8);
  transpose_cvt<<<dim3(1, 16, 16), dim3(256), 0, stream>>>(Wq, Wtq, 1024, 64);
  transpose_cvt<<<dim3(1, 16, 16), dim3(256), 0, stream>>>(Wk, Wtk, 1024, 64);
  transpose_cvt<<<dim3(1, 16, 16), dim3(256), 0, stream>>>(Wv, Wtv, 1024, 64);
  transpose_cvt<<<dim3(16, 16, 1), dim3(256), 0, stream>>>(Wo, Wot, 1024, 1024);
  qkv_gemm<<<dim3(32, 8, 3), dim3(256), 0, stream>>>(qb, kb, vb, Wtq, Wtk, Wtv, bq, bk, bv, Qo, Ko, Vto);
  flash_attn<<<dim3(16, 32), dim3(256), 0, stream>>>(Qo, Ko, Vto, maskb, concat);
  out_gemm<<<dim3(32, 8), dim3(256), 0, stream>>>(concat, Wot, bo, (float*)d_out);
}

// Round 3
// 195.611 us; speedup vs baseline: 1.0762x; 1.0762x over previous
//
#include <hip/hip_runtime.h>
#include <stdint.h>

// MultiHeadAttention: B=2, S=2048, H=16, Dh=64, Dm=1024
// Pipeline: pack(fp32->bf16) -> W transpose + mask pack -> QKV GEMM (MFMA) -> flash attn -> out GEMM
#define DM 1024
#define HNUM 16
#define DH 64
#define BB 2
#define SSEQ 2048

typedef unsigned short ushort_t;
typedef __attribute__((ext_vector_type(8))) short bf16x8;
typedef __attribute__((ext_vector_type(4))) float f32x4;

// 0.125 * log2(e): folded into packed mask so softmax runs in exp2 domain
#define SCALE2 0.18033688011112042f

// ---- bf16 helpers (bit-level) ----
__device__ __forceinline__ ushort_t f2bf(float f) {
  unsigned u = __builtin_bit_cast(unsigned, f);
  u += 0x7FFFu + ((u >> 16) & 1u);  // RNE
  return (ushort_t)(u >> 16);
}
__device__ __forceinline__ float bf2f(ushort_t h) {
  return __builtin_bit_cast(float, (unsigned)h << 16);
}
__device__ __forceinline__ float fast_exp2(float x) {
#if __has_builtin(__builtin_amdgcn_exp2f)
  return __builtin_amdgcn_exp2f(x);
#else
  return exp2f(x);
#endif
}

// ---- async global->LDS, 16B per lane; dest = wave-uniform base + lane*16 ----
typedef const __attribute__((address_space(1))) unsigned int* gas_ptr;
typedef __attribute__((address_space(3))) unsigned int* las_ptr;
__device__ __forceinline__ void gload_lds16(const void* g, void* l) {
  __builtin_amdgcn_global_load_lds((gas_ptr)(uintptr_t)g, (las_ptr)(uintptr_t)l, 16, 0, 0);
}

// ---- fp32 -> bf16 bulk convert (8 elems/thread) ----
__global__ void cvt_f32_bf16(const float* __restrict__ src, ushort_t* __restrict__ dst, int n8) {
  int idx = blockIdx.x * 256 + threadIdx.x;
  if (idx >= n8) return;
  const float4* s4 = (const float4*)src;
  float4 a = s4[idx * 2], c = s4[idx * 2 + 1];
  union { ushort_t h[8]; uint4 u; } o;
  o.h[0] = f2bf(a.x); o.h[1] = f2bf(a.y); o.h[2] = f2bf(a.z); o.h[3] = f2bf(a.w);
  o.h[4] = f2bf(c.x); o.h[5] = f2bf(c.y); o.h[6] = f2bf(c.z); o.h[7] = f2bf(c.w);
  ((uint4*)dst)[idx] = o.u;
}

// ---- mask pack: dst[row][g*64 + c*4 + nj] = bf16(mask[row][g*64 + nj*16 + c] * SCALE2) ----
// One block per row; coalesced f32 read, LDS permute, coalesced uint4 write.
// Write phase: 256 threads x 8 elems = exactly one 2048-elem row (single pass).
__global__ void mask_pack(const float* __restrict__ src, ushort_t* __restrict__ dst) {
  __shared__ ushort_t T[2048];
  const int row = blockIdx.x;
  const int tid = threadIdx.x;
  const float4* s4 = (const float4*)(src + (size_t)row * 2048);
  #pragma unroll
  for (int i = 0; i < 2; ++i) {
    const int v = tid * 2 + i;
    float4 a = s4[v];
    T[v * 4 + 0] = f2bf(a.x * SCALE2);
    T[v * 4 + 1] = f2bf(a.y * SCALE2);
    T[v * 4 + 2] = f2bf(a.z * SCALE2);
    T[v * 4 + 3] = f2bf(a.w * SCALE2);
  }
  __syncthreads();
  {
    const int o = tid * 8;                     // out elem base, 0..2040
    const int g = o >> 6, within = o & 63;
    const int c0 = within >> 2;
    union { ushort_t h[8]; uint4 u; } pk;
    #pragma unroll
    for (int jj = 0; jj < 8; ++jj) {
      const int c = c0 + (jj >> 2), nj = jj & 3;
      pk.h[jj] = T[g * 64 + nj * 16 + c];
    }
    ((uint4*)(dst + (size_t)row * 2048))[o >> 3] = pk.u;
  }
}

// ---- transpose+convert: src fp32 [G][R][C] -> dst bf16 [G][C][R] ----
__global__ void transpose_cvt(const float* __restrict__ src, ushort_t* __restrict__ dst, int R, int C) {
  __shared__ ushort_t T[64][65];
  const int g = blockIdx.z;
  const int r0 = blockIdx.y * 64, c0 = blockIdx.x * 64;
  src += (size_t)g * R * C;
  dst += (size_t)g * R * C;
  const int tid = threadIdx.x;
  #pragma unroll
  for (int i = 0; i < 16; ++i) {
    int idx = i * 256 + tid;
    int r = idx >> 6, c = idx & 63;
    T[r][c] = f2bf(src[(size_t)(r0 + r) * C + c0 + c]);
  }
  __syncthreads();
  #pragma unroll
  for (int i = 0; i < 16; ++i) {
    int idx = i * 256 + tid;
    int cc = idx >> 6, rr = idx & 63;
    dst[(size_t)(c0 + cc) * R + r0 + rr] = T[rr][cc];
  }
}

// ---- shared 128x128-tile GEMM mainloop: C[128,128] = A[128rows,K=1024] * Bm^T, Bm is [n][k] ----
__device__ __forceinline__ void gemm_mainloop_128(const ushort_t* __restrict__ A,
                                                  const ushort_t* __restrict__ Bm,
                                                  f32x4 (&acc)[4][4], int m0, int n0, int l, int w) {
  __shared__ ushort_t As[128 * 64];
  __shared__ ushort_t Bs[128 * 64];
  const int wr = w >> 1, wc = w & 1;
  for (int ks = 0; ks < 16; ++ks) {
    const int k0 = ks * 64;
    #pragma unroll
    for (int it = 0; it < 4; ++it) {
      const int chunk = it * 4 + w;
      const int row = chunk * 8 + (l >> 3);
      const int kc = ((l & 7) * 8) ^ ((row & 7) * 8);  // pre-swizzled source
      gload_lds16(A + (size_t)(m0 + row) * 1024 + k0 + kc, (char*)As + chunk * 1024);
      gload_lds16(Bm + (size_t)(n0 + row) * 1024 + k0 + kc, (char*)Bs + chunk * 1024);
    }
    __syncthreads();
    #pragma unroll
    for (int kk = 0; kk < 2; ++kk) {
      bf16x8 af[4], bfr[4];
      #pragma unroll
      for (int mi = 0; mi < 4; ++mi) {
        const int row = wr * 64 + mi * 16 + (l & 15);
        const int kc = (kk * 32 + (l >> 4) * 8) ^ ((row & 7) * 8);
        af[mi] = *(const bf16x8*)(As + row * 64 + kc);
      }
      #pragma unroll
      for (int ni = 0; ni < 4; ++ni) {
        const int row = wc * 64 + ni * 16 + (l & 15);
        const int kc = (kk * 32 + (l >> 4) * 8) ^ ((row & 7) * 8);
        bfr[ni] = *(const bf16x8*)(Bs + row * 64 + kc);
      }
      #pragma unroll
      for (int mi = 0; mi < 4; ++mi)
        #pragma unroll
        for (int ni = 0; ni < 4; ++ni)
          acc[mi][ni] = __builtin_amdgcn_mfma_f32_16x16x32_bf16(af[mi], bfr[ni], acc[mi][ni], 0, 0, 0);
    }
    __syncthreads();
  }
}

// ---- QKV projection: z=0 Q, z=1 K (layout [b][h][s][e]), z=2 V (transposed [b][h][e][s]) ----
__global__ __launch_bounds__(256, 2) void qkv_gemm(
    const ushort_t* __restrict__ qb, const ushort_t* __restrict__ kb, const ushort_t* __restrict__ vb,
    const ushort_t* __restrict__ Wtq, const ushort_t* __restrict__ Wtk, const ushort_t* __restrict__ Wtv,
    const float* __restrict__ bq, const float* __restrict__ bk, const float* __restrict__ bv,
    ushort_t* __restrict__ Qo, ushort_t* __restrict__ Ko, ushort_t* __restrict__ Vto) {
  const int z = blockIdx.z;
  const ushort_t* A  = z == 0 ? qb : (z == 1 ? kb : vb);
  const ushort_t* Bm = z == 0 ? Wtq : (z == 1 ? Wtk : Wtv);
  const float* bias  = z == 0 ? bq : (z == 1 ? bk : bv);
  ushort_t* out      = z == 0 ? Qo : (z == 1 ? Ko : Vto);
  const int m0 = blockIdx.x * 128, n0 = blockIdx.y * 128;
  const int tid = threadIdx.x, l = tid & 63, w = tid >> 6;
  f32x4 acc[4][4] = {};
  gemm_mainloop_128(A, Bm, acc, m0, n0, l, w);
  const int wr = w >> 1, wc = w & 1;
  #pragma unroll
  for (int mi = 0; mi < 4; ++mi) {
    #pragma unroll
    for (int ni = 0; ni < 4; ++ni) {
      const int n = n0 + wc * 64 + ni * 16 + (l & 15);
      const float bb = bias[n];
      const int mbase = m0 + wr * 64 + mi * 16 + ((l >> 4) << 2);
      if (z < 2) {
        #pragma unroll
        for (int i = 0; i < 4; ++i) {
          const int m = mbase + i;
          const size_t o = (((size_t)((m >> 11) * 16 + (n >> 6))) * 2048 + (m & 2047)) * 64 + (n & 63);
          out[o] = f2bf(acc[mi][ni][i] + bb);
        }
      } else {
        union { ushort_t h[4]; uint2 u2; } pk;
        #pragma unroll
        for (int i = 0; i < 4; ++i) pk.h[i] = f2bf(acc[mi][ni][i] + bb);
        const size_t o = (((size_t)((mbase >> 11) * 16 + (n >> 6))) * 64 + (n & 63)) * 2048 + (mbase & 2047);
        *(uint2*)(out + o) = pk.u2;
      }
    }
  }
}

// ---- output projection: d_out fp32 [4096][1024] ----
__global__ __launch_bounds__(256, 2) void out_gemm(const ushort_t* __restrict__ A,
                                                   const ushort_t* __restrict__ Bm,
                                                   const float* __restrict__ bias,
                                                   float* __restrict__ out) {
  const int m0 = blockIdx.x * 128, n0 = blockIdx.y * 128;
  const int tid = threadIdx.x, l = tid & 63, w = tid >> 6;
  f32x4 acc[4][4] = {};
  gemm_mainloop_128(A, Bm, acc, m0, n0, l, w);
  const int wr = w >> 1, wc = w & 1;
  #pragma unroll
  for (int mi = 0; mi < 4; ++mi) {
    #pragma unroll
    for (int ni = 0; ni < 4; ++ni) {
      const int n = n0 + wc * 64 + ni * 16 + (l & 15);
      const float bb = bias[n];
      const int mbase = m0 + wr * 64 + mi * 16 + ((l >> 4) << 2);
      #pragma unroll
      for (int i = 0; i < 4; ++i)
        out[(size_t)(mbase + i) * 1024 + n] = acc[mi][ni][i] + bb;
    }
  }
}

// ---- flash attention v2: 64 q-rows/block, 4 waves x 16 rows; KVBLK=64, double-buffered K/V ----
__device__ __forceinline__ void stage_kv(const ushort_t* __restrict__ Kb, const ushort_t* __restrict__ Vb,
                                         int t0, ushort_t* ks, ushort_t* vs, int l, int w) {
  #pragma unroll
  for (int half = 0; half < 2; ++half) {
    const int c = half * 4 + w;
    const int r1 = c * 8 + (l >> 3);
    const int cc = ((l & 7) * 8) ^ ((r1 & 7) * 8);  // pre-swizzled source col
    gload_lds16(Kb + (size_t)(t0 + r1) * 64 + cc, (char*)ks + c * 1024);
    gload_lds16(Vb + (size_t)r1 * 2048 + t0 + cc, (char*)vs + c * 1024);
  }
}

__global__ __launch_bounds__(256, 4) void flash_attn(const ushort_t* __restrict__ Q,
                                                     const ushort_t* __restrict__ K,
                                                     const ushort_t* __restrict__ Vt,
                                                     const ushort_t* __restrict__ maskP,
                                                     ushort_t* __restrict__ concat) {
  const int bh = blockIdx.y, b = bh >> 4, h = bh & 15;
  const int s0 = blockIdx.x * 64;
  const int tid = threadIdx.x, l = tid & 63, w = tid >> 6;
  __shared__ ushort_t Ks[2][64 * 64];
  __shared__ ushort_t Vs[2][64 * 64];
  __shared__ ushort_t Pl[4][16 * 64];
  const ushort_t* Qb = Q + (size_t)bh * 2048 * 64;
  const ushort_t* Kb = K + (size_t)bh * 2048 * 64;
  const ushort_t* Vb = Vt + (size_t)bh * 64 * 2048;
  const int qrow = s0 + w * 16;
  const int lr = (l >> 4) << 2;   // C-fragment row group base (0,4,8,12)
  const int lc = l & 15;          // C-fragment col

  // Q fragments in registers for the whole kernel
  bf16x8 aq[2];
  #pragma unroll
  for (int kq = 0; kq < 2; ++kq)
    aq[kq] = *(const bf16x8*)(Qb + (size_t)(qrow + lc) * 64 + kq * 32 + (l >> 4) * 8);

  float m_run[4], l_run[4];
  f32x4 acc_o[4] = {};
  #pragma unroll
  for (int i = 0; i < 4; ++i) { m_run[i] = -1e30f; l_run[i] = 0.f; }

  stage_kv(Kb, Vb, 0, Ks[0], Vs[0], l, w);  // prologue prefetch
  int cur = 0;

  for (int t0 = 0; t0 < 2048; t0 += 64) {
    __syncthreads();  // drains vmcnt(0): cur buffer staged; all waves done with prev buffer
    if (t0 + 64 < 2048) stage_kv(Kb, Vb, t0 + 64, Ks[cur ^ 1], Vs[cur ^ 1], l, w);

    // packed mask loads: 4 x uint2 = 16 bf16 (premultiplied by 0.125*log2e)
    uint2 mpk[4];
    #pragma unroll
    for (int i = 0; i < 4; ++i)
      mpk[i] = *(const uint2*)(maskP + (size_t)(qrow + lr + i) * 2048 + t0 + lc * 4);

    // QK^T: 16 rows x 64 cols
    f32x4 sc[4] = {};
    #pragma unroll
    for (int kq = 0; kq < 2; ++kq) {
      #pragma unroll
      for (int nj = 0; nj < 4; ++nj) {
        const int row = nj * 16 + lc;
        const int kc = (kq * 32 + (l >> 4) * 8) ^ ((row & 7) * 8);
        const bf16x8 bk4 = *(const bf16x8*)(Ks[cur] + row * 64 + kc);
        sc[nj] = __builtin_amdgcn_mfma_f32_16x16x32_bf16(aq[kq], bk4, sc[nj], 0, 0, 0);
      }
    }

    // apply packed mask (scale folded), per-row tile max
    float tmax[4];
    #pragma unroll
    for (int i = 0; i < 4; ++i) {
      const unsigned lo = mpk[i].x, hi = mpk[i].y;
      const float mv0 = bf2f((ushort_t)lo), mv1 = bf2f((ushort_t)(lo >> 16));
      const float mv2 = bf2f((ushort_t)hi), mv3 = bf2f((ushort_t)(hi >> 16));
      float a0 = sc[0][i] * mv0, a1 = sc[1][i] * mv1, a2 = sc[2][i] * mv2, a3 = sc[3][i] * mv3;
      sc[0][i] = a0; sc[1][i] = a1; sc[2][i] = a2; sc[3][i] = a3;
      tmax[i] = fmaxf(fmaxf(a0, a1), fmaxf(a2, a3));
    }
    // row-max across the 16 lanes holding each row; online rescale (exp2 domain)
    #pragma unroll
    for (int i = 0; i < 4; ++i) {
      float v2 = tmax[i];
      v2 = fmaxf(v2, __shfl_xor(v2, 1));
      v2 = fmaxf(v2, __shfl_xor(v2, 2));
      v2 = fmaxf(v2, __shfl_xor(v2, 4));
      v2 = fmaxf(v2, __shfl_xor(v2, 8));
      const float mnew = fmaxf(m_run[i], v2);
      const float rf = fast_exp2(m_run[i] - mnew);
      m_run[i] = mnew;
      l_run[i] *= rf;
      #pragma unroll
      for (int ne = 0; ne < 4; ++ne) acc_o[ne][i] *= rf;
    }

    // P = exp2(s - m), swizzled per-wave LDS write, row sums
    float psum[4] = {0.f, 0.f, 0.f, 0.f};
    #pragma unroll
    for (int nj = 0; nj < 4; ++nj) {
      #pragma unroll
      for (int i = 0; i < 4; ++i) {
        const float p = fast_exp2(sc[nj][i] - m_run[i]);
        psum[i] += p;
        const int r = lr + i;
        const int cb = ((nj * 16 + lc) * 2) ^ ((r & 7) << 4);
        *(ushort_t*)((char*)Pl[w] + r * 128 + cb) = f2bf(p);
      }
    }
    #pragma unroll
    for (int i = 0; i < 4; ++i) {
      float s = psum[i];
      s += __shfl_xor(s, 1); s += __shfl_xor(s, 2);
      s += __shfl_xor(s, 4); s += __shfl_xor(s, 8);
      l_run[i] += s;
    }

    // PV: acc_o += P * V  (V^T rows are k-contiguous MFMA-B operands)
    #pragma unroll
    for (int kt = 0; kt < 2; ++kt) {
      const int cb = ((kt * 32 + (l >> 4) * 8) * 2) ^ ((lc & 7) << 4);
      const bf16x8 ap = *(const bf16x8*)((char*)Pl[w] + lc * 128 + cb);
      #pragma unroll
      for (int ne = 0; ne < 4; ++ne) {
        const int row = ne * 16 + lc;
        const int kc = (kt * 32 + (l >> 4) * 8) ^ ((row & 7) * 8);
        const bf16x8 bv4 = *(const bf16x8*)(Vs[cur] + row * 64 + kc);
        acc_o[ne] = __builtin_amdgcn_mfma_f32_16x16x32_bf16(ap, bv4, acc_o[ne], 0, 0, 0);
      }
    }
    cur ^= 1;
  }

  // normalize and write concat [b][s][h*64+e] (bf16)
  float inv[4];
  #pragma unroll
  for (int i = 0; i < 4; ++i) inv[i] = 1.0f / l_run[i];
  #pragma unroll
  for (int ne = 0; ne < 4; ++ne) {
    const int e = ne * 16 + lc;
    #pragma unroll
    for (int i = 0; i < 4; ++i) {
      const int srow = qrow + lr + i;
      concat[((size_t)(b * 2048 + srow)) * 1024 + h * 64 + e] = f2bf(acc_o[ne][i] * inv[i]);
    }
  }
}

extern "C" void kernel_launch(void* const* d_in, const int* in_sizes, int n_in,
                              void* d_out, int out_size, void* d_ws, size_t ws_size,
                              hipStream_t stream) {
  const float* q    = (const float*)d_in[0];
  const float* k    = (const float*)d_in[1];
  const float* v    = (const float*)d_in[2];
  const float* mask = (const float*)d_in[3];
  const float* Wq   = (const float*)d_in[4];
  const float* bq   = (const float*)d_in[5];
  const float* Wk   = (const float*)d_in[6];
  const float* bk   = (const float*)d_in[7];
  const float* Wv   = (const float*)d_in[8];
  const float* bv   = (const float*)d_in[9];
  const float* Wo   = (const float*)d_in[10];
  const float* bo   = (const float*)d_in[11];

  const size_t SZ8M = (size_t)4096 * 1024 * 2;   // 8 MiB buffers (bf16)
  const size_t SZ2M = (size_t)1024 * 1024 * 2;   // 2 MiB weight buffers
  if (ws_size < 7 * SZ8M + 4 * SZ2M) return;     // need 64 MiB scratch

  char* p = (char*)d_ws;
  ushort_t* qb    = (ushort_t*)p; p += SZ8M;     // reused as `concat` after qkv_gemm
  ushort_t* kb    = (ushort_t*)p; p += SZ8M;
  ushort_t* vb    = (ushort_t*)p; p += SZ8M;
  ushort_t* maskb = (ushort_t*)p; p += SZ8M;     // packed mask (scale*log2e folded)
  ushort_t* Qo    = (ushort_t*)p; p += SZ8M;
  ushort_t* Ko    = (ushort_t*)p; p += SZ8M;
  ushort_t* Vto   = (ushort_t*)p; p += SZ8M;
  ushort_t* Wtq   = (ushort_t*)p; p += SZ2M;
  ushort_t* Wtk   = (ushort_t*)p; p += SZ2M;
  ushort_t* Wtv   = (ushort_t*)p; p += SZ2M;
  ushort_t* Wot   = (ushort_t*)p; p += SZ2M;
  ushort_t* concat = qb;

  const int n8 = (4096 * 1024) / 8;  // 524288
  cvt_f32_bf16<<<dim3(2048), dim3(256), 0, stream>>>(q, qb, n8);
  cvt_f32_bf16<<<dim3(2048), dim3(256), 0, stream>>>(k, kb, n8);
  cvt_f32_bf16<<<dim3(2048), dim3(256), 0, stream>>>(v, vb, n8);
  mask_pack<<<dim3(2048), dim3(256), 0, stream>>>(mask, maskb);
  transpose_cvt<<<dim3(1, 16, 16), dim3(256), 0, stream>>>(Wq, Wtq, 1024, 64);
  transpose_cvt<<<dim3(1, 16, 16), dim3(256), 0, stream>>>(Wk, Wtk, 1024, 64);
  transpose_cvt<<<dim3(1, 16, 16), dim3(256), 0, stream>>>(Wv, Wtv, 1024, 64);
  transpose_cvt<<<dim3(16, 16, 1), dim3(256), 0, stream>>>(Wo, Wot, 1024, 1024);
  qkv_gemm<<<dim3(32, 8, 3), dim3(256), 0, stream>>>(qb, kb, vb, Wtq, Wtk, Wtv, bq, bk, bv, Qo, Ko, Vto);
  flash_attn<<<dim3(32, 32), dim3(256), 0, stream>>>(Qo, Ko, Vto, maskb, concat);
  out_gemm<<<dim3(32, 8), dim3(256), 0, stream>>>(concat, Wot, bo, (float*)d_out);
}

// Round 4
// 151.759 us; speedup vs baseline: 1.3871x; 1.2890x over previous
//
#include <hip/hip_runtime.h>
#include <stdint.h>

// MultiHeadAttention: B=2, S=2048, H=16, Dh=64, Dm=1024
// Pipeline: pack(fp32->bf16) -> W transpose + mask pack -> QKV GEMM (MFMA) -> flash attn (swapped-QK^T, in-reg softmax) -> out GEMM
#define DM 1024
#define HNUM 16
#define DH 64
#define BB 2
#define SSEQ 2048

typedef unsigned short ushort_t;
typedef __attribute__((ext_vector_type(8))) short bf16x8;
typedef __attribute__((ext_vector_type(4))) float f32x4;
typedef __attribute__((ext_vector_type(16))) float f32x16;

// 0.125 * log2(e): folded into packed mask so softmax runs in exp2 domain
#define SCALE2 0.18033688011112042f
#define DEFER_THR 11.0f   // defer-max threshold (exp2 domain); P bounded by 2^11

// ---- bf16 helpers (bit-level) ----
__device__ __forceinline__ ushort_t f2bf(float f) {
  unsigned u = __builtin_bit_cast(unsigned, f);
  u += 0x7FFFu + ((u >> 16) & 1u);  // RNE
  return (ushort_t)(u >> 16);
}
__device__ __forceinline__ float bf2f(ushort_t h) {
  return __builtin_bit_cast(float, (unsigned)h << 16);
}
__device__ __forceinline__ float fast_exp2(float x) {
#if __has_builtin(__builtin_amdgcn_exp2f)
  return __builtin_amdgcn_exp2f(x);
#else
  return exp2f(x);
#endif
}
// packed RNE f32x2 -> bf16x2 (one instruction)
__device__ __forceinline__ unsigned cvt_pk_bf16(float lo, float hi) {
  unsigned r;
  asm("v_cvt_pk_bf16_f32 %0, %1, %2" : "=v"(r) : "v"(lo), "v"(hi));
  return r;
}
// {a',b'} = {{a.lo32,b.lo32},{a.hi32,b.hi32}} lane-halves swap (T12 recipe)
__device__ __forceinline__ void plane32_swap(unsigned& a, unsigned& b, int hh) {
#if __has_builtin(__builtin_amdgcn_permlane32_swap)
  typedef int v2i __attribute__((ext_vector_type(2)));
  v2i r = __builtin_amdgcn_permlane32_swap((int)a, (int)b, 0, 0);
  a = (unsigned)r.x; b = (unsigned)r.y;
#else
  unsigned sa = (unsigned)__shfl_xor((int)a, 32);
  unsigned sb = (unsigned)__shfl_xor((int)b, 32);
  unsigned na = hh ? sb : a;
  unsigned nb = hh ? b : sa;
  a = na; b = nb;
#endif
}

// ---- async global->LDS, 16B per lane; dest = wave-uniform base + lane*16 ----
typedef const __attribute__((address_space(1))) unsigned int* gas_ptr;
typedef __attribute__((address_space(3))) unsigned int* las_ptr;
__device__ __forceinline__ void gload_lds16(const void* g, void* l) {
  __builtin_amdgcn_global_load_lds((gas_ptr)(uintptr_t)g, (las_ptr)(uintptr_t)l, 16, 0, 0);
}

// ---- fp32 -> bf16 bulk convert (8 elems/thread) ----
__global__ void cvt_f32_bf16(const float* __restrict__ src, ushort_t* __restrict__ dst, int n8) {
  int idx = blockIdx.x * 256 + threadIdx.x;
  if (idx >= n8) return;
  const float4* s4 = (const float4*)src;
  float4 a = s4[idx * 2], c = s4[idx * 2 + 1];
  union { ushort_t h[8]; uint4 u; } o;
  o.h[0] = f2bf(a.x); o.h[1] = f2bf(a.y); o.h[2] = f2bf(a.z); o.h[3] = f2bf(a.w);
  o.h[4] = f2bf(c.x); o.h[5] = f2bf(c.y); o.h[6] = f2bf(c.z); o.h[7] = f2bf(c.w);
  ((uint4*)dst)[idx] = o.u;
}

// ---- mask pack for swapped-QK^T fragment layout ----
// word index wd = (a*4+g2)*64 + l  (a: 32-t acc, g2: reg group, l: lane)
// elem j of word: (q = G*32 + (l&31), t = T*64 + 32a + 8g2 + 4*(l>>5) + j), premult SCALE2
__global__ void mask_pack(const float* __restrict__ src, ushort_t* __restrict__ dst) {
  const int TG = blockIdx.x;           // T*64 + G
  const int T = TG >> 6, G = TG & 63;
  const int tid = threadIdx.x;
  #pragma unroll
  for (int i = 0; i < 2; ++i) {
    const int wd = tid * 2 + i;        // [0,512)
    const int l = wd & 63, g2 = (wd >> 6) & 3, a = wd >> 8;
    const int q = G * 32 + (l & 31);
    const int t = T * 64 + a * 32 + g2 * 8 + (l >> 5) * 4;
    float4 mv = *(const float4*)(src + (size_t)q * 2048 + t);
    union { ushort_t h4[4]; uint2 u; } pk;
    pk.h4[0] = f2bf(mv.x * SCALE2); pk.h4[1] = f2bf(mv.y * SCALE2);
    pk.h4[2] = f2bf(mv.z * SCALE2); pk.h4[3] = f2bf(mv.w * SCALE2);
    *(uint2*)(dst + (size_t)TG * 2048 + (size_t)wd * 4) = pk.u;
  }
}

// ---- transpose+convert: src fp32 [G][R][C] -> dst bf16 [G][C][R] ----
__global__ void transpose_cvt(const float* __restrict__ src, ushort_t* __restrict__ dst, int R, int C) {
  __shared__ ushort_t T[64][65];
  const int g = blockIdx.z;
  const int r0 = blockIdx.y * 64, c0 = blockIdx.x * 64;
  src += (size_t)g * R * C;
  dst += (size_t)g * R * C;
  const int tid = threadIdx.x;
  #pragma unroll
  for (int i = 0; i < 16; ++i) {
    int idx = i * 256 + tid;
    int r = idx >> 6, c = idx & 63;
    T[r][c] = f2bf(src[(size_t)(r0 + r) * C + c0 + c]);
  }
  __syncthreads();
  #pragma unroll
  for (int i = 0; i < 16; ++i) {
    int idx = i * 256 + tid;
    int cc = idx >> 6, rr = idx & 63;
    dst[(size_t)(c0 + cc) * R + r0 + rr] = T[rr][cc];
  }
}

// ---- shared 128x128-tile GEMM mainloop: C[128,128] = A[128rows,K=1024] * Bm^T, Bm is [n][k] ----
__device__ __forceinline__ void gemm_mainloop_128(const ushort_t* __restrict__ A,
                                                  const ushort_t* __restrict__ Bm,
                                                  f32x4 (&acc)[4][4], int m0, int n0, int l, int w) {
  __shared__ ushort_t As[128 * 64];
  __shared__ ushort_t Bs[128 * 64];
  const int wr = w >> 1, wc = w & 1;
  for (int ks = 0; ks < 16; ++ks) {
    const int k0 = ks * 64;
    #pragma unroll
    for (int it = 0; it < 4; ++it) {
      const int chunk = it * 4 + w;
      const int row = chunk * 8 + (l >> 3);
      const int kc = ((l & 7) * 8) ^ ((row & 7) * 8);  // pre-swizzled source
      gload_lds16(A + (size_t)(m0 + row) * 1024 + k0 + kc, (char*)As + chunk * 1024);
      gload_lds16(Bm + (size_t)(n0 + row) * 1024 + k0 + kc, (char*)Bs + chunk * 1024);
    }
    __syncthreads();
    #pragma unroll
    for (int kk = 0; kk < 2; ++kk) {
      bf16x8 af[4], bfr[4];
      #pragma unroll
      for (int mi = 0; mi < 4; ++mi) {
        const int row = wr * 64 + mi * 16 + (l & 15);
        const int kc = (kk * 32 + (l >> 4) * 8) ^ ((row & 7) * 8);
        af[mi] = *(const bf16x8*)(As + row * 64 + kc);
      }
      #pragma unroll
      for (int ni = 0; ni < 4; ++ni) {
        const int row = wc * 64 + ni * 16 + (l & 15);
        const int kc = (kk * 32 + (l >> 4) * 8) ^ ((row & 7) * 8);
        bfr[ni] = *(const bf16x8*)(Bs + row * 64 + kc);
      }
      #pragma unroll
      for (int mi = 0; mi < 4; ++mi)
        #pragma unroll
        for (int ni = 0; ni < 4; ++ni)
          acc[mi][ni] = __builtin_amdgcn_mfma_f32_16x16x32_bf16(af[mi], bfr[ni], acc[mi][ni], 0, 0, 0);
    }
    __syncthreads();
  }
}

// ---- QKV projection: z=0 Q, z=1 K (layout [b][h][s][e]), z=2 V (transposed [b][h][e][s]) ----
__global__ __launch_bounds__(256, 2) void qkv_gemm(
    const ushort_t* __restrict__ qb, const ushort_t* __restrict__ kb, const ushort_t* __restrict__ vb,
    const ushort_t* __restrict__ Wtq, const ushort_t* __restrict__ Wtk, const ushort_t* __restrict__ Wtv,
    const float* __restrict__ bq, const float* __restrict__ bk, const float* __restrict__ bv,
    ushort_t* __restrict__ Qo, ushort_t* __restrict__ Ko, ushort_t* __restrict__ Vto) {
  const int z = blockIdx.z;
  const ushort_t* A  = z == 0 ? qb : (z == 1 ? kb : vb);
  const ushort_t* Bm = z == 0 ? Wtq : (z == 1 ? Wtk : Wtv);
  const float* bias  = z == 0 ? bq : (z == 1 ? bk : bv);
  ushort_t* out      = z == 0 ? Qo : (z == 1 ? Ko : Vto);
  const int m0 = blockIdx.x * 128, n0 = blockIdx.y * 128;
  const int tid = threadIdx.x, l = tid & 63, w = tid >> 6;
  f32x4 acc[4][4] = {};
  gemm_mainloop_128(A, Bm, acc, m0, n0, l, w);
  const int wr = w >> 1, wc = w & 1;
  #pragma unroll
  for (int mi = 0; mi < 4; ++mi) {
    #pragma unroll
    for (int ni = 0; ni < 4; ++ni) {
      const int n = n0 + wc * 64 + ni * 16 + (l & 15);
      const float bb = bias[n];
      const int mbase = m0 + wr * 64 + mi * 16 + ((l >> 4) << 2);
      if (z < 2) {
        #pragma unroll
        for (int i = 0; i < 4; ++i) {
          const int m = mbase + i;
          const size_t o = (((size_t)((m >> 11) * 16 + (n >> 6))) * 2048 + (m & 2047)) * 64 + (n & 63);
          out[o] = f2bf(acc[mi][ni][i] + bb);
        }
      } else {
        union { ushort_t h[4]; uint2 u2; } pk;
        #pragma unroll
        for (int i = 0; i < 4; ++i) pk.h[i] = f2bf(acc[mi][ni][i] + bb);
        const size_t o = (((size_t)((mbase >> 11) * 16 + (n >> 6))) * 64 + (n & 63)) * 2048 + (mbase & 2047);
        *(uint2*)(out + o) = pk.u2;
      }
    }
  }
}

// ---- output projection: d_out fp32 [4096][1024] ----
__global__ __launch_bounds__(256, 2) void out_gemm(const ushort_t* __restrict__ A,
                                                   const ushort_t* __restrict__ Bm,
                                                   const float* __restrict__ bias,
                                                   float* __restrict__ out) {
  const int m0 = blockIdx.x * 128, n0 = blockIdx.y * 128;
  const int tid = threadIdx.x, l = tid & 63, w = tid >> 6;
  f32x4 acc[4][4] = {};
  gemm_mainloop_128(A, Bm, acc, m0, n0, l, w);
  const int wr = w >> 1, wc = w & 1;
  #pragma unroll
  for (int mi = 0; mi < 4; ++mi) {
    #pragma unroll
    for (int ni = 0; ni < 4; ++ni) {
      const int n = n0 + wc * 64 + ni * 16 + (l & 15);
      const float bb = bias[n];
      const int mbase = m0 + wr * 64 + mi * 16 + ((l >> 4) << 2);
      #pragma unroll
      for (int i = 0; i < 4; ++i)
        out[(size_t)(mbase + i) * 1024 + n] = acc[mi][ni][i] + bb;
    }
  }
}

// ---- flash attention v3: swapped QK^T (32x32 MFMA), in-register softmax ----
// Block: 4 waves x 32 q-rows = 128 q-rows; KVBLK=64 double-buffered.
// Lane l: q = l&31 (C-col), hh = l>>5; S^T rows t = 32a + (r&3)+8*(r>>2)+4*hh.
__device__ __forceinline__ void stage_kv(const ushort_t* __restrict__ Kb, const ushort_t* __restrict__ Vb,
                                         int t0, ushort_t* ks, ushort_t* vs, int l, int w) {
  #pragma unroll
  for (int half = 0; half < 2; ++half) {
    const int c = half * 4 + w;
    const int r1 = c * 8 + (l >> 3);
    const int cc = ((l & 7) * 8) ^ ((r1 & 7) * 8);  // pre-swizzled source col
    gload_lds16(Kb + (size_t)(t0 + r1) * 64 + cc, (char*)ks + c * 1024);
    gload_lds16(Vb + (size_t)r1 * 2048 + t0 + cc, (char*)vs + c * 1024);
  }
}

__global__ __launch_bounds__(256, 2) void flash_attn(const ushort_t* __restrict__ Q,
                                                     const ushort_t* __restrict__ K,
                                                     const ushort_t* __restrict__ Vt,
                                                     const ushort_t* __restrict__ maskF,
                                                     ushort_t* __restrict__ concat) {
  const int bh = blockIdx.y, b = bh >> 4, h = bh & 15;
  const int tid = threadIdx.x, l = tid & 63, w = tid >> 6;
  const int hh = l >> 5, q_l = l & 31;
  __shared__ ushort_t Ks[2][64 * 64];
  __shared__ ushort_t Vs[2][64 * 64];
  const ushort_t* Qb = Q + (size_t)bh * 2048 * 64;
  const ushort_t* Kb = K + (size_t)bh * 2048 * 64;
  const ushort_t* Vb = Vt + (size_t)bh * 64 * 2048;
  const int qbase = blockIdx.x * 128 + w * 32;
  const int G = qbase >> 5;

  // Q as MFMA-B fragments: lane holds col q=l&31, k = s*16 + hh*8 + j
  bf16x8 qf[4];
  #pragma unroll
  for (int s = 0; s < 4; ++s)
    qf[s] = *(const bf16x8*)(Qb + (size_t)(qbase + q_l) * 64 + s * 16 + hh * 8);

  float m_run = -1e30f, l_run = 0.f;
  f32x16 po[2] = {};  // O^T accumulators (e-tiles), col q = l&31

  stage_kv(Kb, Vb, 0, Ks[0], Vs[0], l, w);
  int cur = 0;

  for (int t0 = 0; t0 < 2048; t0 += 64) {
    __syncthreads();  // cur staged (vmcnt drain), prev buffer free
    if (t0 + 64 < 2048) stage_kv(Kb, Vb, t0 + 64, Ks[cur ^ 1], Vs[cur ^ 1], l, w);

    // packed mask: 8 coalesced uint2 loads
    const ushort_t* mbase = maskF + (size_t)((t0 >> 6) * 64 + G) * 2048;
    uint2 mw[2][4];
    #pragma unroll
    for (int a = 0; a < 2; ++a)
      #pragma unroll
      for (int g2 = 0; g2 < 4; ++g2)
        mw[a][g2] = *(const uint2*)(mbase + (size_t)(((a * 4 + g2) * 64) + l) * 4);

    // S^T = K * Q^T : 2 t-tiles x 4 k-steps
    f32x16 sc[2] = {};
    #pragma unroll
    for (int s = 0; s < 4; ++s) {
      #pragma unroll
      for (int mt = 0; mt < 2; ++mt) {
        const int row = mt * 32 + q_l;
        const int col = (s * 16 + hh * 8) ^ ((row & 7) * 8);
        const bf16x8 kf = *(const bf16x8*)(Ks[cur] + row * 64 + col);
        sc[mt] = __builtin_amdgcn_mfma_f32_32x32x16_bf16(kf, qf[s], sc[mt], 0, 0, 0);
      }
    }

    // mask multiply (scale*log2e folded) + in-register row max
    float tmax = -1e30f;
    #pragma unroll
    for (int a = 0; a < 2; ++a) {
      #pragma unroll
      for (int g2 = 0; g2 < 4; ++g2) {
        const unsigned lo = mw[a][g2].x, hi = mw[a][g2].y;
        float v0 = sc[a][g2 * 4 + 0] * bf2f((ushort_t)lo);
        float v1 = sc[a][g2 * 4 + 1] * bf2f((ushort_t)(lo >> 16));
        float v2 = sc[a][g2 * 4 + 2] * bf2f((ushort_t)hi);
        float v3 = sc[a][g2 * 4 + 3] * bf2f((ushort_t)(hi >> 16));
        sc[a][g2 * 4 + 0] = v0; sc[a][g2 * 4 + 1] = v1;
        sc[a][g2 * 4 + 2] = v2; sc[a][g2 * 4 + 3] = v3;
        tmax = fmaxf(tmax, fmaxf(fmaxf(v0, v1), fmaxf(v2, v3)));
      }
    }
    tmax = fmaxf(tmax, __shfl_xor(tmax, 32));  // partner half holds other 32 t

    // defer-max online rescale (T13): skip O-rescale while growth <= THR
    if (!__all(tmax <= m_run + DEFER_THR)) {
      const float mnew = fmaxf(m_run, tmax);
      const float rf = fast_exp2(m_run - mnew);
      m_run = mnew;
      l_run *= rf;
      #pragma unroll
      for (int et = 0; et < 2; ++et)
        #pragma unroll
        for (int r = 0; r < 16; ++r) po[et][r] *= rf;
    }

    // P = exp2(s - m), row-sum, pack to bf16 words (T12)
    float psum = 0.f;
    unsigned pw[2][8];
    #pragma unroll
    for (int a = 0; a < 2; ++a)
      #pragma unroll
      for (int j = 0; j < 8; ++j) {
        const float p0 = fast_exp2(sc[a][2 * j] - m_run);
        const float p1 = fast_exp2(sc[a][2 * j + 1] - m_run);
        psum += p0 + p1;
        pw[a][j] = cvt_pk_bf16(p0, p1);
      }
    psum += __shfl_xor(psum, 32);
    l_run += psum;

    // redistribute halves: (k0,k2),(k1,k3),(k4,k6),(k5,k7) swaps build B-frag word order
    #pragma unroll
    for (int a = 0; a < 2; ++a) {
      plane32_swap(pw[a][0], pw[a][2], hh);
      plane32_swap(pw[a][1], pw[a][3], hh);
      plane32_swap(pw[a][4], pw[a][6], hh);
      plane32_swap(pw[a][5], pw[a][7], hh);
    }

    // O^T += V^T * P : A = V^T tile rows e, B = P
    #pragma unroll
    for (int s = 0; s < 4; ++s) {
      union { unsigned u[4]; bf16x8 v; } pf;
      pf.u[0] = pw[s >> 1][(s & 1) * 4 + 0];
      pf.u[1] = pw[s >> 1][(s & 1) * 4 + 1];
      pf.u[2] = pw[s >> 1][(s & 1) * 4 + 2];
      pf.u[3] = pw[s >> 1][(s & 1) * 4 + 3];
      #pragma unroll
      for (int et = 0; et < 2; ++et) {
        const int row = et * 32 + q_l;
        const int col = (s * 16 + hh * 8) ^ ((row & 7) * 8);
        const bf16x8 vf = *(const bf16x8*)(Vs[cur] + row * 64 + col);
        po[et] = __builtin_amdgcn_mfma_f32_32x32x16_bf16(vf, pf.v, po[et], 0, 0, 0);
      }
    }
    cur ^= 1;
  }

  // epilogue: normalize, transpose O^T->O via LDS (reuse Ks region), coalesced store
  const float invl = 1.0f / l_run;
  __syncthreads();
  ushort_t* ow = &Ks[0][0] + w * 2048;  // 4KB per wave (32q x 64e)
  #pragma unroll
  for (int et = 0; et < 2; ++et)
    #pragma unroll
    for (int r = 0; r < 16; ++r) {
      const int e = et * 32 + (r & 3) + 8 * (r >> 2) + 4 * hh;
      const int ba = (q_l * 128 + e * 2) ^ ((q_l & 7) << 4);
      *(ushort_t*)((char*)ow + ba) = f2bf(po[et][r] * invl);
    }
  __syncthreads();
  {
    union { ushort_t hs[32]; uint2 u2[8]; uint4 u4[4]; } ov;
    const int ebase = hh * 32;
    #pragma unroll
    for (int c = 0; c < 8; ++c) {
      const int e0 = ebase + c * 4;
      const int ba = (q_l * 128 + e0 * 2) ^ ((q_l & 7) << 4);
      ov.u2[c] = *(const uint2*)((const char*)ow + ba);
    }
    ushort_t* dst = concat + ((size_t)(b * 2048 + qbase + q_l)) * 1024 + h * 64 + ebase;
    #pragma unroll
    for (int c2 = 0; c2 < 4; ++c2)
      ((uint4*)dst)[c2] = ov.u4[c2];
  }
}

extern "C" void kernel_launch(void* const* d_in, const int* in_sizes, int n_in,
                              void* d_out, int out_size, void* d_ws, size_t ws_size,
                              hipStream_t stream) {
  const float* q    = (const float*)d_in[0];
  const float* k    = (const float*)d_in[1];
  const float* v    = (const float*)d_in[2];
  const float* mask = (const float*)d_in[3];
  const float* Wq   = (const float*)d_in[4];
  const float* bq   = (const float*)d_in[5];
  const float* Wk   = (const float*)d_in[6];
  const float* bk   = (const float*)d_in[7];
  const float* Wv   = (const float*)d_in[8];
  const float* bv   = (const float*)d_in[9];
  const float* Wo   = (const float*)d_in[10];
  const float* bo   = (const float*)d_in[11];

  const size_t SZ8M = (size_t)4096 * 1024 * 2;   // 8 MiB buffers (bf16)
  const size_t SZ2M = (size_t)1024 * 1024 * 2;   // 2 MiB weight buffers
  if (ws_size < 7 * SZ8M + 4 * SZ2M) return;     // need 64 MiB scratch

  char* p = (char*)d_ws;
  ushort_t* qb    = (ushort_t*)p; p += SZ8M;     // reused as `concat` after qkv_gemm
  ushort_t* kb    = (ushort_t*)p; p += SZ8M;
  ushort_t* vb    = (ushort_t*)p; p += SZ8M;
  ushort_t* maskb = (ushort_t*)p; p += SZ8M;     // fragment-packed mask
  ushort_t* Qo    = (ushort_t*)p; p += SZ8M;
  ushort_t* Ko    = (ushort_t*)p; p += SZ8M;
  ushort_t* Vto   = (ushort_t*)p; p += SZ8M;
  ushort_t* Wtq   = (ushort_t*)p; p += SZ2M;
  ushort_t* Wtk   = (ushort_t*)p; p += SZ2M;
  ushort_t* Wtv   = (ushort_t*)p; p += SZ2M;
  ushort_t* Wot   = (ushort_t*)p; p += SZ2M;
  ushort_t* concat = qb;

  const int n8 = (4096 * 1024) / 8;  // 524288
  cvt_f32_bf16<<<dim3(2048), dim3(256), 0, stream>>>(q, qb, n8);
  cvt_f32_bf16<<<dim3(2048), dim3(256), 0, stream>>>(k, kb, n8);
  cvt_f32_bf16<<<dim3(2048), dim3(256), 0, stream>>>(v, vb, n8);
  mask_pack<<<dim3(2048), dim3(256), 0, stream>>>(mask, maskb);
  transpose_cvt<<<dim3(1, 16, 16), dim3(256), 0, stream>>>(Wq, Wtq, 1024, 64);
  transpose_cvt<<<dim3(1, 16, 16), dim3(256), 0, stream>>>(Wk, Wtk, 1024, 64);
  transpose_cvt<<<dim3(1, 16, 16), dim3(256), 0, stream>>>(Wv, Wtv, 1024, 64);
  transpose_cvt<<<dim3(16, 16, 1), dim3(256), 0, stream>>>(Wo, Wot, 1024, 1024);
  qkv_gemm<<<dim3(32, 8, 3), dim3(256), 0, stream>>>(qb, kb, vb, Wtq, Wtk, Wtv, bq, bk, bv, Qo, Ko, Vto);
  flash_attn<<<dim3(16, 32), dim3(256), 0, stream>>>(Qo, Ko, Vto, maskb, concat);
  out_gemm<<<dim3(32, 8), dim3(256), 0, stream>>>(concat, Wot, bo, (float*)d_out);
}

// Round 5
// 144.718 us; speedup vs baseline: 1.4546x; 1.0486x over previous
//
#include <hip/hip_runtime.h>
#include <stdint.h>

// MultiHeadAttention: B=2, S=2048, H=16, Dh=64, Dm=1024
// Pipeline: cvt3 -> mask_pack + W transposes -> QKV GEMM -> flash attn (swapped QK^T, in-reg softmax, KVBLK=128) -> out GEMM
#define DM 1024
#define HNUM 16
#define DH 64
#define BB 2
#define SSEQ 2048

typedef unsigned short ushort_t;
typedef __attribute__((ext_vector_type(8))) short bf16x8;
typedef __attribute__((ext_vector_type(4))) float f32x4;
typedef __attribute__((ext_vector_type(16))) float f32x16;

// 0.125 * log2(e): folded into packed mask so softmax runs in exp2 domain
#define SCALE2 0.18033688011112042f
#define DEFER_THR 11.0f   // defer-max threshold (exp2 domain); P bounded by 2^11

// ---- bf16 helpers (bit-level) ----
__device__ __forceinline__ ushort_t f2bf(float f) {
  unsigned u = __builtin_bit_cast(unsigned, f);
  u += 0x7FFFu + ((u >> 16) & 1u);  // RNE
  return (ushort_t)(u >> 16);
}
__device__ __forceinline__ float bf2f(ushort_t h) {
  return __builtin_bit_cast(float, (unsigned)h << 16);
}
__device__ __forceinline__ float fast_exp2(float x) {
#if __has_builtin(__builtin_amdgcn_exp2f)
  return __builtin_amdgcn_exp2f(x);
#else
  return exp2f(x);
#endif
}
// packed RNE f32x2 -> bf16x2 (one instruction)
__device__ __forceinline__ unsigned cvt_pk_bf16(float lo, float hi) {
  unsigned r;
  asm("v_cvt_pk_bf16_f32 %0, %1, %2" : "=v"(r) : "v"(lo), "v"(hi));
  return r;
}
// {a',b'}: a' = {a[0:31], b[0:31]}, b' = {a[32:63], b[32:63]}
__device__ __forceinline__ void plane32_swap(unsigned& a, unsigned& b, int hh) {
#if __has_builtin(__builtin_amdgcn_permlane32_swap)
  typedef int v2i __attribute__((ext_vector_type(2)));
  v2i r = __builtin_amdgcn_permlane32_swap((int)a, (int)b, 0, 0);
  a = (unsigned)r.x; b = (unsigned)r.y;
#else
  unsigned sa = (unsigned)__shfl_xor((int)a, 32);
  unsigned sb = (unsigned)__shfl_xor((int)b, 32);
  unsigned na = hh ? sb : a;
  unsigned nb = hh ? b : sa;
  a = na; b = nb;
#endif
}
// cross-half (lane l <-> l^32) reductions via permlane32_swap: 1 VALU op vs ds_bpermute
__device__ __forceinline__ float xhalf_max(float x, int hh) {
  unsigned a = __builtin_bit_cast(unsigned, x), b = a;
  plane32_swap(a, b, hh);
  return fmaxf(__builtin_bit_cast(float, a), __builtin_bit_cast(float, b));
}
__device__ __forceinline__ float xhalf_sum(float x, int hh) {
  unsigned a = __builtin_bit_cast(unsigned, x), b = a;
  plane32_swap(a, b, hh);
  return __builtin_bit_cast(float, a) + __builtin_bit_cast(float, b);
}

// ---- async global->LDS, 16B per lane; dest = wave-uniform base + lane*16 ----
typedef const __attribute__((address_space(1))) unsigned int* gas_ptr;
typedef __attribute__((address_space(3))) unsigned int* las_ptr;
__device__ __forceinline__ void gload_lds16(const void* g, void* l) {
  __builtin_amdgcn_global_load_lds((gas_ptr)(uintptr_t)g, (las_ptr)(uintptr_t)l, 16, 0, 0);
}

// ---- fp32 -> bf16 bulk convert, 3 tensors in one launch (8 elems/thread) ----
__global__ void cvt3_f32_bf16(const float* __restrict__ q, const float* __restrict__ k,
                              const float* __restrict__ v,
                              ushort_t* __restrict__ qd, ushort_t* __restrict__ kd,
                              ushort_t* __restrict__ vd) {
  const int z = blockIdx.y;
  const float* src = z == 0 ? q : (z == 1 ? k : v);
  ushort_t* dst    = z == 0 ? qd : (z == 1 ? kd : vd);
  const int idx = blockIdx.x * 256 + threadIdx.x;
  const float4* s4 = (const float4*)src;
  float4 a = s4[idx * 2], c = s4[idx * 2 + 1];
  union { ushort_t h[8]; uint4 u; } o;
  o.h[0] = f2bf(a.x); o.h[1] = f2bf(a.y); o.h[2] = f2bf(a.z); o.h[3] = f2bf(a.w);
  o.h[4] = f2bf(c.x); o.h[5] = f2bf(c.y); o.h[6] = f2bf(c.z); o.h[7] = f2bf(c.w);
  ((uint4*)dst)[idx] = o.u;
}

// ---- mask pack for swapped-QK^T fragment layout ----
// word index wd = (a*4+g2)*64 + l ; elem j: (q = G*32 + (l&31), t = T*64 + 32a + 8g2 + 4*(l>>5) + j)
__global__ void mask_pack(const float* __restrict__ src, ushort_t* __restrict__ dst) {
  const int TG = blockIdx.x;           // T*64 + G
  const int T = TG >> 6, G = TG & 63;
  const int tid = threadIdx.x;
  #pragma unroll
  for (int i = 0; i < 2; ++i) {
    const int wd = tid * 2 + i;        // [0,512)
    const int l = wd & 63, g2 = (wd >> 6) & 3, a = wd >> 8;
    const int q = G * 32 + (l & 31);
    const int t = T * 64 + a * 32 + g2 * 8 + (l >> 5) * 4;
    float4 mv = *(const float4*)(src + (size_t)q * 2048 + t);
    union { ushort_t h4[4]; uint2 u; } pk;
    pk.h4[0] = f2bf(mv.x * SCALE2); pk.h4[1] = f2bf(mv.y * SCALE2);
    pk.h4[2] = f2bf(mv.z * SCALE2); pk.h4[3] = f2bf(mv.w * SCALE2);
    *(uint2*)(dst + (size_t)TG * 2048 + (size_t)wd * 4) = pk.u;
  }
}

// ---- transpose+convert for QKV weights, 3 mats x 16 heads in one launch ----
__global__ void transpose_cvt3(const float* __restrict__ Wq, const float* __restrict__ Wk,
                               const float* __restrict__ Wv,
                               ushort_t* __restrict__ dq, ushort_t* __restrict__ dk,
                               ushort_t* __restrict__ dv) {
  __shared__ ushort_t T[64][65];
  const int mat = blockIdx.z >> 4, g = blockIdx.z & 15;
  const float* src = (mat == 0 ? Wq : (mat == 1 ? Wk : Wv)) + (size_t)g * 1024 * 64;
  ushort_t* dst    = (mat == 0 ? dq : (mat == 1 ? dk : dv)) + (size_t)g * 1024 * 64;
  const int r0 = blockIdx.y * 64;
  const int tid = threadIdx.x;
  #pragma unroll
  for (int i = 0; i < 16; ++i) {
    int idx = i * 256 + tid;
    int r = idx >> 6, c = idx & 63;
    T[r][c] = f2bf(src[(size_t)(r0 + r) * 64 + c]);
  }
  __syncthreads();
  #pragma unroll
  for (int i = 0; i < 16; ++i) {
    int idx = i * 256 + tid;
    int cc = idx >> 6, rr = idx & 63;
    dst[(size_t)cc * 1024 + r0 + rr] = T[rr][cc];
  }
}

// ---- transpose+convert: src fp32 [R][C] -> dst bf16 [C][R] (for W_o) ----
__global__ void transpose_cvt(const float* __restrict__ src, ushort_t* __restrict__ dst, int R, int C) {
  __shared__ ushort_t T[64][65];
  const int r0 = blockIdx.y * 64, c0 = blockIdx.x * 64;
  const int tid = threadIdx.x;
  #pragma unroll
  for (int i = 0; i < 16; ++i) {
    int idx = i * 256 + tid;
    int r = idx >> 6, c = idx & 63;
    T[r][c] = f2bf(src[(size_t)(r0 + r) * C + c0 + c]);
  }
  __syncthreads();
  #pragma unroll
  for (int i = 0; i < 16; ++i) {
    int idx = i * 256 + tid;
    int cc = idx >> 6, rr = idx & 63;
    dst[(size_t)(c0 + cc) * R + r0 + rr] = T[rr][cc];
  }
}

// ---- 128x128-tile GEMM mainloop: C[128,128] = A[128rows,K=1024] * Bm^T, Bm is [n][k] ----
__device__ __forceinline__ void gemm_mainloop_128(const ushort_t* __restrict__ A,
                                                  const ushort_t* __restrict__ Bm,
                                                  f32x4 (&acc)[4][4], int m0, int n0, int l, int w) {
  __shared__ ushort_t As[128 * 64];
  __shared__ ushort_t Bs[128 * 64];
  const int wr = w >> 1, wc = w & 1;
  for (int ks = 0; ks < 16; ++ks) {
    const int k0 = ks * 64;
    #pragma unroll
    for (int it = 0; it < 4; ++it) {
      const int chunk = it * 4 + w;
      const int row = chunk * 8 + (l >> 3);
      const int kc = ((l & 7) * 8) ^ ((row & 7) * 8);  // pre-swizzled source
      gload_lds16(A + (size_t)(m0 + row) * 1024 + k0 + kc, (char*)As + chunk * 1024);
      gload_lds16(Bm + (size_t)(n0 + row) * 1024 + k0 + kc, (char*)Bs + chunk * 1024);
    }
    __syncthreads();
    #pragma unroll
    for (int kk = 0; kk < 2; ++kk) {
      bf16x8 af[4], bfr[4];
      #pragma unroll
      for (int mi = 0; mi < 4; ++mi) {
        const int row = wr * 64 + mi * 16 + (l & 15);
        const int kc = (kk * 32 + (l >> 4) * 8) ^ ((row & 7) * 8);
        af[mi] = *(const bf16x8*)(As + row * 64 + kc);
      }
      #pragma unroll
      for (int ni = 0; ni < 4; ++ni) {
        const int row = wc * 64 + ni * 16 + (l & 15);
        const int kc = (kk * 32 + (l >> 4) * 8) ^ ((row & 7) * 8);
        bfr[ni] = *(const bf16x8*)(Bs + row * 64 + kc);
      }
      #pragma unroll
      for (int mi = 0; mi < 4; ++mi)
        #pragma unroll
        for (int ni = 0; ni < 4; ++ni)
          acc[mi][ni] = __builtin_amdgcn_mfma_f32_16x16x32_bf16(af[mi], bfr[ni], acc[mi][ni], 0, 0, 0);
    }
    __syncthreads();
  }
}

// ---- QKV projection: z=0 Q, z=1 K (layout [b][h][s][e]), z=2 V (transposed [b][h][e][s]) ----
__global__ __launch_bounds__(256, 2) void qkv_gemm(
    const ushort_t* __restrict__ qb, const ushort_t* __restrict__ kb, const ushort_t* __restrict__ vb,
    const ushort_t* __restrict__ Wtq, const ushort_t* __restrict__ Wtk, const ushort_t* __restrict__ Wtv,
    const float* __restrict__ bq, const float* __restrict__ bk, const float* __restrict__ bv,
    ushort_t* __restrict__ Qo, ushort_t* __restrict__ Ko, ushort_t* __restrict__ Vto) {
  const int z = blockIdx.z;
  const ushort_t* A  = z == 0 ? qb : (z == 1 ? kb : vb);
  const ushort_t* Bm = z == 0 ? Wtq : (z == 1 ? Wtk : Wtv);
  const float* bias  = z == 0 ? bq : (z == 1 ? bk : bv);
  ushort_t* out      = z == 0 ? Qo : (z == 1 ? Ko : Vto);
  const int m0 = blockIdx.x * 128, n0 = blockIdx.y * 128;
  const int tid = threadIdx.x, l = tid & 63, w = tid >> 6;
  f32x4 acc[4][4] = {};
  gemm_mainloop_128(A, Bm, acc, m0, n0, l, w);
  const int wr = w >> 1, wc = w & 1;
  #pragma unroll
  for (int mi = 0; mi < 4; ++mi) {
    #pragma unroll
    for (int ni = 0; ni < 4; ++ni) {
      const int n = n0 + wc * 64 + ni * 16 + (l & 15);
      const float bb = bias[n];
      const int mbase = m0 + wr * 64 + mi * 16 + ((l >> 4) << 2);
      if (z < 2) {
        #pragma unroll
        for (int i = 0; i < 4; ++i) {
          const int m = mbase + i;
          const size_t o = (((size_t)((m >> 11) * 16 + (n >> 6))) * 2048 + (m & 2047)) * 64 + (n & 63);
          out[o] = f2bf(acc[mi][ni][i] + bb);
        }
      } else {
        union { ushort_t h[4]; uint2 u2; } pk;
        #pragma unroll
        for (int i = 0; i < 4; ++i) pk.h[i] = f2bf(acc[mi][ni][i] + bb);
        const size_t o = (((size_t)((mbase >> 11) * 16 + (n >> 6))) * 64 + (n & 63)) * 2048 + (mbase & 2047);
        *(uint2*)(out + o) = pk.u2;
      }
    }
  }
}

// ---- output projection: 64x128 tiles (512 blocks = 2/CU), d_out fp32 [4096][1024] ----
__global__ __launch_bounds__(256, 2) void out_gemm(const ushort_t* __restrict__ A,
                                                   const ushort_t* __restrict__ Bm,
                                                   const float* __restrict__ bias,
                                                   float* __restrict__ out) {
  __shared__ ushort_t As[64 * 64];
  __shared__ ushort_t Bs[128 * 64];
  const int m0 = blockIdx.x * 64, n0 = blockIdx.y * 128;
  const int tid = threadIdx.x, l = tid & 63, w = tid >> 6;
  const int wr = w >> 1, wc = w & 1;
  f32x4 acc[2][4] = {};
  for (int ks = 0; ks < 16; ++ks) {
    const int k0 = ks * 64;
    #pragma unroll
    for (int it = 0; it < 6; ++it) {
      const int chunk = it * 4 + w;     // 0..23: 0-7 -> As, 8-23 -> Bs
      if (chunk < 8) {
        const int row = chunk * 8 + (l >> 3);
        const int kc = ((l & 7) * 8) ^ ((row & 7) * 8);
        gload_lds16(A + (size_t)(m0 + row) * 1024 + k0 + kc, (char*)As + chunk * 1024);
      } else {
        const int c2 = chunk - 8;
        const int row = c2 * 8 + (l >> 3);
        const int kc = ((l & 7) * 8) ^ ((row & 7) * 8);
        gload_lds16(Bm + (size_t)(n0 + row) * 1024 + k0 + kc, (char*)Bs + c2 * 1024);
      }
    }
    __syncthreads();
    #pragma unroll
    for (int kk = 0; kk < 2; ++kk) {
      bf16x8 af[2], bfr[4];
      #pragma unroll
      for (int mi = 0; mi < 2; ++mi) {
        const int row = wr * 32 + mi * 16 + (l & 15);
        const int kc = (kk * 32 + (l >> 4) * 8) ^ ((row & 7) * 8);
        af[mi] = *(const bf16x8*)(As + row * 64 + kc);
      }
      #pragma unroll
      for (int ni = 0; ni < 4; ++ni) {
        const int row = wc * 64 + ni * 16 + (l & 15);
        const int kc = (kk * 32 + (l >> 4) * 8) ^ ((row & 7) * 8);
        bfr[ni] = *(const bf16x8*)(Bs + row * 64 + kc);
      }
      #pragma unroll
      for (int mi = 0; mi < 2; ++mi)
        #pragma unroll
        for (int ni = 0; ni < 4; ++ni)
          acc[mi][ni] = __builtin_amdgcn_mfma_f32_16x16x32_bf16(af[mi], bfr[ni], acc[mi][ni], 0, 0, 0);
    }
    __syncthreads();
  }
  #pragma unroll
  for (int mi = 0; mi < 2; ++mi) {
    #pragma unroll
    for (int ni = 0; ni < 4; ++ni) {
      const int n = n0 + wc * 64 + ni * 16 + (l & 15);
      const float bb = bias[n];
      const int mbase = m0 + wr * 32 + mi * 16 + ((l >> 4) << 2);
      #pragma unroll
      for (int i = 0; i < 4; ++i)
        out[(size_t)(mbase + i) * 1024 + n] = acc[mi][ni][i] + bb;
    }
  }
}

// ---- flash attention v4: swapped QK^T (32x32 MFMA), in-reg softmax, KVBLK=128 ----
// Block: 4 waves x 32 q-rows = 128 q-rows; per barrier-pair: 2 x 64-t sub-tiles.
__device__ __forceinline__ void stage_kv128(const ushort_t* __restrict__ Kb, const ushort_t* __restrict__ Vb,
                                            int t0, ushort_t* ks, ushort_t* vs, int l, int w) {
  // K tile [128][64] bf16 (16KB): 16 chunks of 1KB (8 t-rows each)
  #pragma unroll
  for (int i = 0; i < 4; ++i) {
    const int c = i * 4 + w;
    const int r1 = c * 8 + (l >> 3);                 // t-row 0..127
    const int cc = ((l & 7) * 8) ^ ((r1 & 7) * 8);   // pre-swizzled source col
    gload_lds16(Kb + (size_t)(t0 + r1) * 64 + cc, (char*)ks + c * 1024);
  }
  // V^T tile [64][128] bf16 (16KB): 16 chunks of 1KB (4 e-rows each)
  #pragma unroll
  for (int i = 0; i < 4; ++i) {
    const int c = i * 4 + w;
    const int r1 = c * 4 + (l >> 4);                 // e-row 0..63
    const int cc = ((l & 15) * 8) ^ ((r1 & 7) * 8);  // XOR hits bits 3-5 only
    gload_lds16(Vb + (size_t)r1 * 2048 + t0 + cc, (char*)vs + c * 1024);
  }
}

__global__ __launch_bounds__(256, 2) void flash_attn(const ushort_t* __restrict__ Q,
                                                     const ushort_t* __restrict__ K,
                                                     const ushort_t* __restrict__ Vt,
                                                     const ushort_t* __restrict__ maskF,
                                                     ushort_t* __restrict__ concat) {
  const int bh = blockIdx.y, b = bh >> 4, h = bh & 15;
  const int tid = threadIdx.x, l = tid & 63, w = tid >> 6;
  const int hh = l >> 5, q_l = l & 31;
  __shared__ ushort_t Ks[2][128 * 64];
  __shared__ ushort_t Vs[2][64 * 128];
  const ushort_t* Qb = Q + (size_t)bh * 2048 * 64;
  const ushort_t* Kb = K + (size_t)bh * 2048 * 64;
  const ushort_t* Vb = Vt + (size_t)bh * 64 * 2048;
  const int qbase = blockIdx.x * 128 + w * 32;
  const int G = qbase >> 5;

  // Q as MFMA-B fragments: lane holds col q=l&31, k = s*16 + hh*8 + j
  bf16x8 qf[4];
  #pragma unroll
  for (int s = 0; s < 4; ++s)
    qf[s] = *(const bf16x8*)(Qb + (size_t)(qbase + q_l) * 64 + s * 16 + hh * 8);

  float m_run = -1e30f, l_run = 0.f;
  f32x16 po[2] = {};  // O^T accumulators (e-tiles), col q = l&31

  stage_kv128(Kb, Vb, 0, Ks[0], Vs[0], l, w);
  int cur = 0;

  for (int t0 = 0; t0 < 2048; t0 += 128) {
    __syncthreads();  // cur staged (vmcnt drain), prev buffer free
    if (t0 + 128 < 2048) stage_kv128(Kb, Vb, t0 + 128, Ks[cur ^ 1], Vs[cur ^ 1], l, w);

    #pragma unroll
    for (int sub = 0; sub < 2; ++sub) {
      // packed mask: 8 coalesced uint2 loads
      const ushort_t* mbase = maskF + (size_t)(((t0 >> 6) + sub) * 64 + G) * 2048;
      uint2 mw[2][4];
      #pragma unroll
      for (int a = 0; a < 2; ++a)
        #pragma unroll
        for (int g2 = 0; g2 < 4; ++g2)
          mw[a][g2] = *(const uint2*)(mbase + (size_t)(((a * 4 + g2) * 64) + l) * 4);

      // S^T = K * Q^T : 2 t-tiles x 4 k-steps
      f32x16 sc[2] = {};
      __builtin_amdgcn_s_setprio(1);
      #pragma unroll
      for (int s = 0; s < 4; ++s) {
        #pragma unroll
        for (int mt = 0; mt < 2; ++mt) {
          const int row = sub * 64 + mt * 32 + q_l;
          const int col = (s * 16 + hh * 8) ^ ((q_l & 7) * 8);
          const bf16x8 kf = *(const bf16x8*)(Ks[cur] + row * 64 + col);
          sc[mt] = __builtin_amdgcn_mfma_f32_32x32x16_bf16(kf, qf[s], sc[mt], 0, 0, 0);
        }
      }
      __builtin_amdgcn_s_setprio(0);

      // mask multiply (scale*log2e folded) + in-register row max
      float tmax = -1e30f;
      #pragma unroll
      for (int a = 0; a < 2; ++a) {
        #pragma unroll
        for (int g2 = 0; g2 < 4; ++g2) {
          const unsigned lo = mw[a][g2].x, hi = mw[a][g2].y;
          float v0 = sc[a][g2 * 4 + 0] * bf2f((ushort_t)lo);
          float v1 = sc[a][g2 * 4 + 1] * bf2f((ushort_t)(lo >> 16));
          float v2 = sc[a][g2 * 4 + 2] * bf2f((ushort_t)hi);
          float v3 = sc[a][g2 * 4 + 3] * bf2f((ushort_t)(hi >> 16));
          sc[a][g2 * 4 + 0] = v0; sc[a][g2 * 4 + 1] = v1;
          sc[a][g2 * 4 + 2] = v2; sc[a][g2 * 4 + 3] = v3;
          tmax = fmaxf(tmax, fmaxf(fmaxf(v0, v1), fmaxf(v2, v3)));
        }
      }
      tmax = xhalf_max(tmax, hh);  // partner half holds other 32 t

      // defer-max online rescale (T13): skip O-rescale while growth <= THR
      if (!__all(tmax <= m_run + DEFER_THR)) {
        const float mnew = fmaxf(m_run, tmax);
        const float rf = fast_exp2(m_run - mnew);
        m_run = mnew;
        l_run *= rf;
        #pragma unroll
        for (int et = 0; et < 2; ++et)
          #pragma unroll
          for (int r = 0; r < 16; ++r) po[et][r] *= rf;
      }

      // P = exp2(s - m), row-sum, pack to bf16 words (T12)
      float psum = 0.f;
      unsigned pw[2][8];
      #pragma unroll
      for (int a = 0; a < 2; ++a)
        #pragma unroll
        for (int j = 0; j < 8; ++j) {
          const float p0 = fast_exp2(sc[a][2 * j] - m_run);
          const float p1 = fast_exp2(sc[a][2 * j + 1] - m_run);
          psum += p0 + p1;
          pw[a][j] = cvt_pk_bf16(p0, p1);
        }
      l_run += xhalf_sum(psum, hh);

      // redistribute halves: build PV B-fragment word order
      #pragma unroll
      for (int a = 0; a < 2; ++a) {
        plane32_swap(pw[a][0], pw[a][2], hh);
        plane32_swap(pw[a][1], pw[a][3], hh);
        plane32_swap(pw[a][4], pw[a][6], hh);
        plane32_swap(pw[a][5], pw[a][7], hh);
      }

      // O^T += V^T * P : A = V^T tile rows e, B = P
      __builtin_amdgcn_s_setprio(1);
      #pragma unroll
      for (int s = 0; s < 4; ++s) {
        union { unsigned u[4]; bf16x8 v; } pf;
        pf.u[0] = pw[s >> 1][(s & 1) * 4 + 0];
        pf.u[1] = pw[s >> 1][(s & 1) * 4 + 1];
        pf.u[2] = pw[s >> 1][(s & 1) * 4 + 2];
        pf.u[3] = pw[s >> 1][(s & 1) * 4 + 3];
        #pragma unroll
        for (int et = 0; et < 2; ++et) {
          const int row = et * 32 + q_l;
          const int col = sub * 64 + ((s * 16 + hh * 8) ^ ((q_l & 7) * 8));
          const bf16x8 vf = *(const bf16x8*)(Vs[cur] + row * 128 + col);
          po[et] = __builtin_amdgcn_mfma_f32_32x32x16_bf16(vf, pf.v, po[et], 0, 0, 0);
        }
      }
      __builtin_amdgcn_s_setprio(0);
    }
    cur ^= 1;
  }

  // epilogue: normalize, transpose O^T->O via LDS (reuse Ks region), coalesced store
  const float invl = 1.0f / l_run;
  __syncthreads();
  ushort_t* ow = &Ks[0][0] + w * 2048;  // 4KB per wave (32q x 64e)
  #pragma unroll
  for (int et = 0; et < 2; ++et)
    #pragma unroll
    for (int r = 0; r < 16; ++r) {
      const int e = et * 32 + (r & 3) + 8 * (r >> 2) + 4 * hh;
      const int ba = (q_l * 128 + e * 2) ^ ((q_l & 7) << 4);
      *(ushort_t*)((char*)ow + ba) = f2bf(po[et][r] * invl);
    }
  __syncthreads();
  {
    union { ushort_t hs[32]; uint2 u2[8]; uint4 u4[4]; } ov;
    const int ebase = hh * 32;
    #pragma unroll
    for (int c = 0; c < 8; ++c) {
      const int e0 = ebase + c * 4;
      const int ba = (q_l * 128 + e0 * 2) ^ ((q_l & 7) << 4);
      ov.u2[c] = *(const uint2*)((const char*)ow + ba);
    }
    ushort_t* dst = concat + ((size_t)(b * 2048 + qbase + q_l)) * 1024 + h * 64 + ebase;
    #pragma unroll
    for (int c2 = 0; c2 < 4; ++c2)
      ((uint4*)dst)[c2] = ov.u4[c2];
  }
}

extern "C" void kernel_launch(void* const* d_in, const int* in_sizes, int n_in,
                              void* d_out, int out_size, void* d_ws, size_t ws_size,
                              hipStream_t stream) {
  const float* q    = (const float*)d_in[0];
  const float* k    = (const float*)d_in[1];
  const float* v    = (const float*)d_in[2];
  const float* mask = (const float*)d_in[3];
  const float* Wq   = (const float*)d_in[4];
  const float* bq   = (const float*)d_in[5];
  const float* Wk   = (const float*)d_in[6];
  const float* bk   = (const float*)d_in[7];
  const float* Wv   = (const float*)d_in[8];
  const float* bv   = (const float*)d_in[9];
  const float* Wo   = (const float*)d_in[10];
  const float* bo   = (const float*)d_in[11];

  const size_t SZ8M = (size_t)4096 * 1024 * 2;   // 8 MiB buffers (bf16)
  const size_t SZ2M = (size_t)1024 * 1024 * 2;   // 2 MiB weight buffers
  if (ws_size < 7 * SZ8M + 4 * SZ2M) return;     // need 64 MiB scratch

  char* p = (char*)d_ws;
  ushort_t* qb    = (ushort_t*)p; p += SZ8M;     // reused as `concat` after qkv_gemm
  ushort_t* kb    = (ushort_t*)p; p += SZ8M;
  ushort_t* vb    = (ushort_t*)p; p += SZ8M;
  ushort_t* maskb = (ushort_t*)p; p += SZ8M;     // fragment-packed mask
  ushort_t* Qo    = (ushort_t*)p; p += SZ8M;
  ushort_t* Ko    = (ushort_t*)p; p += SZ8M;
  ushort_t* Vto   = (ushort_t*)p; p += SZ8M;
  ushort_t* Wtq   = (ushort_t*)p; p += SZ2M;
  ushort_t* Wtk   = (ushort_t*)p; p += SZ2M;
  ushort_t* Wtv   = (ushort_t*)p; p += SZ2M;
  ushort_t* Wot   = (ushort_t*)p; p += SZ2M;
  ushort_t* concat = qb;

  cvt3_f32_bf16<<<dim3(2048, 3), dim3(256), 0, stream>>>(q, k, v, qb, kb, vb);
  mask_pack<<<dim3(2048), dim3(256), 0, stream>>>(mask, maskb);
  transpose_cvt3<<<dim3(1, 16, 48), dim3(256), 0, stream>>>(Wq, Wk, Wv, Wtq, Wtk, Wtv);
  transpose_cvt<<<dim3(16, 16), dim3(256), 0, stream>>>(Wo, Wot, 1024, 1024);
  qkv_gemm<<<dim3(32, 8, 3), dim3(256), 0, stream>>>(qb, kb, vb, Wtq, Wtk, Wtv, bq, bk, bv, Qo, Ko, Vto);
  flash_attn<<<dim3(16, 32), dim3(256), 0, stream>>>(Qo, Ko, Vto, maskb, concat);
  out_gemm<<<dim3(64, 8), dim3(256), 0, stream>>>(concat, Wot, bo, (float*)d_out);
}

// Round 6
// 141.838 us; speedup vs baseline: 1.4842x; 1.0203x over previous
//
#include <hip/hip_runtime.h>
#include <stdint.h>

// MultiHeadAttention: B=2, S=2048, H=16, Dh=64, Dm=1024
// Pipeline: cvt3 -> mask_pack + W transposes -> QKV GEMM -> flash attn (swapped QK^T, in-reg softmax) -> out GEMM
#define DM 1024
#define HNUM 16
#define DH 64
#define BB 2
#define SSEQ 2048

typedef unsigned short ushort_t;
typedef __attribute__((ext_vector_type(8))) short bf16x8;
typedef __attribute__((ext_vector_type(4))) float f32x4;
typedef __attribute__((ext_vector_type(16))) float f32x16;

// 0.125 * log2(e): folded into packed mask so softmax runs in exp2 domain
#define SCALE2 0.18033688011112042f
#define DEFER_THR 11.0f   // defer-max threshold (exp2 domain); P bounded by 2^11

// ---- bf16 helpers (bit-level) ----
__device__ __forceinline__ ushort_t f2bf(float f) {
  unsigned u = __builtin_bit_cast(unsigned, f);
  u += 0x7FFFu + ((u >> 16) & 1u);  // RNE
  return (ushort_t)(u >> 16);
}
__device__ __forceinline__ float bf2f(ushort_t h) {
  return __builtin_bit_cast(float, (unsigned)h << 16);
}
__device__ __forceinline__ float fast_exp2(float x) {
#if __has_builtin(__builtin_amdgcn_exp2f)
  return __builtin_amdgcn_exp2f(x);
#else
  return exp2f(x);
#endif
}
// packed RNE f32x2 -> bf16x2 (one instruction)
__device__ __forceinline__ unsigned cvt_pk_bf16(float lo, float hi) {
  unsigned r;
  asm("v_cvt_pk_bf16_f32 %0, %1, %2" : "=v"(r) : "v"(lo), "v"(hi));
  return r;
}
// {a',b'}: a' = {a[0:31], b[0:31]}, b' = {a[32:63], b[32:63]}
__device__ __forceinline__ void plane32_swap(unsigned& a, unsigned& b, int hh) {
#if __has_builtin(__builtin_amdgcn_permlane32_swap)
  typedef int v2i __attribute__((ext_vector_type(2)));
  v2i r = __builtin_amdgcn_permlane32_swap((int)a, (int)b, 0, 0);
  a = (unsigned)r.x; b = (unsigned)r.y;
#else
  unsigned sa = (unsigned)__shfl_xor((int)a, 32);
  unsigned sb = (unsigned)__shfl_xor((int)b, 32);
  unsigned na = hh ? sb : a;
  unsigned nb = hh ? b : sa;
  a = na; b = nb;
#endif
}
// cross-half (lane l <-> l^32) reductions via permlane32_swap
__device__ __forceinline__ float xhalf_max(float x, int hh) {
  unsigned a = __builtin_bit_cast(unsigned, x), b = a;
  plane32_swap(a, b, hh);
  return fmaxf(__builtin_bit_cast(float, a), __builtin_bit_cast(float, b));
}
__device__ __forceinline__ float xhalf_sum(float x, int hh) {
  unsigned a = __builtin_bit_cast(unsigned, x), b = a;
  plane32_swap(a, b, hh);
  return __builtin_bit_cast(float, a) + __builtin_bit_cast(float, b);
}

// ---- async global->LDS, 16B per lane; dest = wave-uniform base + lane*16 ----
typedef const __attribute__((address_space(1))) unsigned int* gas_ptr;
typedef __attribute__((address_space(3))) unsigned int* las_ptr;
__device__ __forceinline__ void gload_lds16(const void* g, void* l) {
  __builtin_amdgcn_global_load_lds((gas_ptr)(uintptr_t)g, (las_ptr)(uintptr_t)l, 16, 0, 0);
}

// ---- fp32 -> bf16 bulk convert, 3 tensors in one launch (8 elems/thread) ----
__global__ void cvt3_f32_bf16(const float* __restrict__ q, const float* __restrict__ k,
                              const float* __restrict__ v,
                              ushort_t* __restrict__ qd, ushort_t* __restrict__ kd,
                              ushort_t* __restrict__ vd) {
  const int z = blockIdx.y;
  const float* src = z == 0 ? q : (z == 1 ? k : v);
  ushort_t* dst    = z == 0 ? qd : (z == 1 ? kd : vd);
  const int idx = blockIdx.x * 256 + threadIdx.x;
  const float4* s4 = (const float4*)src;
  float4 a = s4[idx * 2], c = s4[idx * 2 + 1];
  union { ushort_t h[8]; uint4 u; } o;
  o.h[0] = f2bf(a.x); o.h[1] = f2bf(a.y); o.h[2] = f2bf(a.z); o.h[3] = f2bf(a.w);
  o.h[4] = f2bf(c.x); o.h[5] = f2bf(c.y); o.h[6] = f2bf(c.z); o.h[7] = f2bf(c.w);
  ((uint4*)dst)[idx] = o.u;
}

// ---- mask pack for swapped-QK^T fragment layout ----
// word index wd = (a*4+g2)*64 + l ; elem j: (q = G*32 + (l&31), t = T*64 + 32a + 8g2 + 4*(l>>5) + j)
__global__ void mask_pack(const float* __restrict__ src, ushort_t* __restrict__ dst) {
  const int TG = blockIdx.x;           // T*64 + G
  const int T = TG >> 6, G = TG & 63;
  const int tid = threadIdx.x;
  #pragma unroll
  for (int i = 0; i < 2; ++i) {
    const int wd = tid * 2 + i;        // [0,512)
    const int l = wd & 63, g2 = (wd >> 6) & 3, a = wd >> 8;
    const int q = G * 32 + (l & 31);
    const int t = T * 64 + a * 32 + g2 * 8 + (l >> 5) * 4;
    float4 mv = *(const float4*)(src + (size_t)q * 2048 + t);
    union { ushort_t h4[4]; uint2 u; } pk;
    pk.h4[0] = f2bf(mv.x * SCALE2); pk.h4[1] = f2bf(mv.y * SCALE2);
    pk.h4[2] = f2bf(mv.z * SCALE2); pk.h4[3] = f2bf(mv.w * SCALE2);
    *(uint2*)(dst + (size_t)TG * 2048 + (size_t)wd * 4) = pk.u;
  }
}

// ---- transpose+convert for QKV weights, 3 mats x 16 heads in one launch ----
__global__ void transpose_cvt3(const float* __restrict__ Wq, const float* __restrict__ Wk,
                               const float* __restrict__ Wv,
                               ushort_t* __restrict__ dq, ushort_t* __restrict__ dk,
                               ushort_t* __restrict__ dv) {
  __shared__ ushort_t T[64][65];
  const int mat = blockIdx.z >> 4, g = blockIdx.z & 15;
  const float* src = (mat == 0 ? Wq : (mat == 1 ? Wk : Wv)) + (size_t)g * 1024 * 64;
  ushort_t* dst    = (mat == 0 ? dq : (mat == 1 ? dk : dv)) + (size_t)g * 1024 * 64;
  const int r0 = blockIdx.y * 64;
  const int tid = threadIdx.x;
  #pragma unroll
  for (int i = 0; i < 16; ++i) {
    int idx = i * 256 + tid;
    int r = idx >> 6, c = idx & 63;
    T[r][c] = f2bf(src[(size_t)(r0 + r) * 64 + c]);
  }
  __syncthreads();
  #pragma unroll
  for (int i = 0; i < 16; ++i) {
    int idx = i * 256 + tid;
    int cc = idx >> 6, rr = idx & 63;
    dst[(size_t)cc * 1024 + r0 + rr] = T[rr][cc];
  }
}

// ---- transpose+convert: src fp32 [R][C] -> dst bf16 [C][R] (for W_o) ----
__global__ void transpose_cvt(const float* __restrict__ src, ushort_t* __restrict__ dst, int R, int C) {
  __shared__ ushort_t T[64][65];
  const int r0 = blockIdx.y * 64, c0 = blockIdx.x * 64;
  const int tid = threadIdx.x;
  #pragma unroll
  for (int i = 0; i < 16; ++i) {
    int idx = i * 256 + tid;
    int r = idx >> 6, c = idx & 63;
    T[r][c] = f2bf(src[(size_t)(r0 + r) * C + c0 + c]);
  }
  __syncthreads();
  #pragma unroll
  for (int i = 0; i < 16; ++i) {
    int idx = i * 256 + tid;
    int cc = idx >> 6, rr = idx & 63;
    dst[(size_t)(c0 + cc) * R + r0 + rr] = T[rr][cc];
  }
}

// ---- 128x128-tile GEMM mainloop: C[128,128] = A[128rows,K=1024] * Bm^T, Bm is [n][k] ----
__device__ __forceinline__ void gemm_mainloop_128(const ushort_t* __restrict__ A,
                                                  const ushort_t* __restrict__ Bm,
                                                  f32x4 (&acc)[4][4], int m0, int n0, int l, int w) {
  __shared__ ushort_t As[128 * 64];
  __shared__ ushort_t Bs[128 * 64];
  const int wr = w >> 1, wc = w & 1;
  for (int ks = 0; ks < 16; ++ks) {
    const int k0 = ks * 64;
    #pragma unroll
    for (int it = 0; it < 4; ++it) {
      const int chunk = it * 4 + w;
      const int row = chunk * 8 + (l >> 3);
      const int kc = ((l & 7) * 8) ^ ((row & 7) * 8);  // pre-swizzled source
      gload_lds16(A + (size_t)(m0 + row) * 1024 + k0 + kc, (char*)As + chunk * 1024);
      gload_lds16(Bm + (size_t)(n0 + row) * 1024 + k0 + kc, (char*)Bs + chunk * 1024);
    }
    __syncthreads();
    #pragma unroll
    for (int kk = 0; kk < 2; ++kk) {
      bf16x8 af[4], bfr[4];
      #pragma unroll
      for (int mi = 0; mi < 4; ++mi) {
        const int row = wr * 64 + mi * 16 + (l & 15);
        const int kc = (kk * 32 + (l >> 4) * 8) ^ ((row & 7) * 8);
        af[mi] = *(const bf16x8*)(As + row * 64 + kc);
      }
      #pragma unroll
      for (int ni = 0; ni < 4; ++ni) {
        const int row = wc * 64 + ni * 16 + (l & 15);
        const int kc = (kk * 32 + (l >> 4) * 8) ^ ((row & 7) * 8);
        bfr[ni] = *(const bf16x8*)(Bs + row * 64 + kc);
      }
      #pragma unroll
      for (int mi = 0; mi < 4; ++mi)
        #pragma unroll
        for (int ni = 0; ni < 4; ++ni)
          acc[mi][ni] = __builtin_amdgcn_mfma_f32_16x16x32_bf16(af[mi], bfr[ni], acc[mi][ni], 0, 0, 0);
    }
    __syncthreads();
  }
}

// ---- QKV projection: z=0 Q, z=1 K (layout [b][h][s][e]), z=2 V (transposed [b][h][e][s]) ----
__global__ __launch_bounds__(256, 2) void qkv_gemm(
    const ushort_t* __restrict__ qb, const ushort_t* __restrict__ kb, const ushort_t* __restrict__ vb,
    const ushort_t* __restrict__ Wtq, const ushort_t* __restrict__ Wtk, const ushort_t* __restrict__ Wtv,
    const float* __restrict__ bq, const float* __restrict__ bk, const float* __restrict__ bv,
    ushort_t* __restrict__ Qo, ushort_t* __restrict__ Ko, ushort_t* __restrict__ Vto) {
  const int z = blockIdx.z;
  const ushort_t* A  = z == 0 ? qb : (z == 1 ? kb : vb);
  const ushort_t* Bm = z == 0 ? Wtq : (z == 1 ? Wtk : Wtv);
  const float* bias  = z == 0 ? bq : (z == 1 ? bk : bv);
  ushort_t* out      = z == 0 ? Qo : (z == 1 ? Ko : Vto);
  const int m0 = blockIdx.x * 128, n0 = blockIdx.y * 128;
  const int tid = threadIdx.x, l = tid & 63, w = tid >> 6;
  f32x4 acc[4][4] = {};
  gemm_mainloop_128(A, Bm, acc, m0, n0, l, w);
  const int wr = w >> 1, wc = w & 1;
  #pragma unroll
  for (int mi = 0; mi < 4; ++mi) {
    #pragma unroll
    for (int ni = 0; ni < 4; ++ni) {
      const int n = n0 + wc * 64 + ni * 16 + (l & 15);
      const float bb = bias[n];
      const int mbase = m0 + wr * 64 + mi * 16 + ((l >> 4) << 2);
      if (z < 2) {
        #pragma unroll
        for (int i = 0; i < 4; ++i) {
          const int m = mbase + i;
          const size_t o = (((size_t)((m >> 11) * 16 + (n >> 6))) * 2048 + (m & 2047)) * 64 + (n & 63);
          out[o] = f2bf(acc[mi][ni][i] + bb);
        }
      } else {
        union { ushort_t h[4]; uint2 u2; } pk;
        #pragma unroll
        for (int i = 0; i < 4; ++i) pk.h[i] = f2bf(acc[mi][ni][i] + bb);
        const size_t o = (((size_t)((mbase >> 11) * 16 + (n >> 6))) * 64 + (n & 63)) * 2048 + (mbase & 2047);
        *(uint2*)(out + o) = pk.u2;
      }
    }
  }
}

// ---- output projection: 64x128 tiles (512 blocks = 2/CU), d_out fp32 [4096][1024] ----
__global__ __launch_bounds__(256, 2) void out_gemm(const ushort_t* __restrict__ A,
                                                   const ushort_t* __restrict__ Bm,
                                                   const float* __restrict__ bias,
                                                   float* __restrict__ out) {
  __shared__ ushort_t As[64 * 64];
  __shared__ ushort_t Bs[128 * 64];
  const int m0 = blockIdx.x * 64, n0 = blockIdx.y * 128;
  const int tid = threadIdx.x, l = tid & 63, w = tid >> 6;
  const int wr = w >> 1, wc = w & 1;
  f32x4 acc[2][4] = {};
  for (int ks = 0; ks < 16; ++ks) {
    const int k0 = ks * 64;
    #pragma unroll
    for (int it = 0; it < 6; ++it) {
      const int chunk = it * 4 + w;     // 0..23: 0-7 -> As, 8-23 -> Bs
      if (chunk < 8) {
        const int row = chunk * 8 + (l >> 3);
        const int kc = ((l & 7) * 8) ^ ((row & 7) * 8);
        gload_lds16(A + (size_t)(m0 + row) * 1024 + k0 + kc, (char*)As + chunk * 1024);
      } else {
        const int c2 = chunk - 8;
        const int row = c2 * 8 + (l >> 3);
        const int kc = ((l & 7) * 8) ^ ((row & 7) * 8);
        gload_lds16(Bm + (size_t)(n0 + row) * 1024 + k0 + kc, (char*)Bs + c2 * 1024);
      }
    }
    __syncthreads();
    #pragma unroll
    for (int kk = 0; kk < 2; ++kk) {
      bf16x8 af[2], bfr[4];
      #pragma unroll
      for (int mi = 0; mi < 2; ++mi) {
        const int row = wr * 32 + mi * 16 + (l & 15);
        const int kc = (kk * 32 + (l >> 4) * 8) ^ ((row & 7) * 8);
        af[mi] = *(const bf16x8*)(As + row * 64 + kc);
      }
      #pragma unroll
      for (int ni = 0; ni < 4; ++ni) {
        const int row = wc * 64 + ni * 16 + (l & 15);
        const int kc = (kk * 32 + (l >> 4) * 8) ^ ((row & 7) * 8);
        bfr[ni] = *(const bf16x8*)(Bs + row * 64 + kc);
      }
      #pragma unroll
      for (int mi = 0; mi < 2; ++mi)
        #pragma unroll
        for (int ni = 0; ni < 4; ++ni)
          acc[mi][ni] = __builtin_amdgcn_mfma_f32_16x16x32_bf16(af[mi], bfr[ni], acc[mi][ni], 0, 0, 0);
    }
    __syncthreads();
  }
  #pragma unroll
  for (int mi = 0; mi < 2; ++mi) {
    #pragma unroll
    for (int ni = 0; ni < 4; ++ni) {
      const int n = n0 + wc * 64 + ni * 16 + (l & 15);
      const float bb = bias[n];
      const int mbase = m0 + wr * 32 + mi * 16 + ((l >> 4) << 2);
      #pragma unroll
      for (int i = 0; i < 4; ++i)
        out[(size_t)(mbase + i) * 1024 + n] = acc[mi][ni][i] + bb;
    }
  }
}

// ---- flash attention v5: swapped QK^T, in-reg softmax, KVBLK=64, 2-wave blocks ----
// Block: 2 waves x 32 q-rows = 64 q-rows; grid (32,32) = 1024 blocks = 4 blocks/CU.
__global__ __launch_bounds__(128, 2) void flash_attn(const ushort_t* __restrict__ Q,
                                                     const ushort_t* __restrict__ K,
                                                     const ushort_t* __restrict__ Vt,
                                                     const ushort_t* __restrict__ maskF,
                                                     ushort_t* __restrict__ concat) {
  const int bh = blockIdx.y, b = bh >> 4, h = bh & 15;
  const int tid = threadIdx.x, l = tid & 63, w = tid >> 6;  // w in {0,1}
  const int hh = l >> 5, q_l = l & 31;
  __shared__ ushort_t Ks[2][64 * 64];
  __shared__ ushort_t Vs[2][64 * 64];
  const ushort_t* Qb = Q + (size_t)bh * 2048 * 64;
  const ushort_t* Kb = K + (size_t)bh * 2048 * 64;
  const ushort_t* Vb = Vt + (size_t)bh * 64 * 2048;
  const int qbase = blockIdx.x * 64 + w * 32;
  const int G = qbase >> 5;

  // Q as MFMA-B fragments: lane holds col q=l&31, k = s*16 + hh*8 + j
  bf16x8 qf[4];
  #pragma unroll
  for (int s = 0; s < 4; ++s)
    qf[s] = *(const bf16x8*)(Qb + (size_t)(qbase + q_l) * 64 + s * 16 + hh * 8);

  float m_run = -1e30f, l_run = 0.f;
  f32x16 po[2] = {};  // O^T accumulators (e-tiles), col q = l&31

  // stage one 64-t K tile + V^T tile into buf (2 waves: 4 chunks each per tensor)
  auto stage = [&](int t0, ushort_t* ks, ushort_t* vs) {
    #pragma unroll
    for (int i = 0; i < 4; ++i) {
      const int c = i * 2 + w;
      const int r1 = c * 8 + (l >> 3);
      const int cc = ((l & 7) * 8) ^ ((r1 & 7) * 8);  // pre-swizzled source col
      gload_lds16(Kb + (size_t)(t0 + r1) * 64 + cc, (char*)ks + c * 1024);
      gload_lds16(Vb + (size_t)r1 * 2048 + t0 + cc, (char*)vs + c * 1024);
    }
  };
  auto loadmask = [&](int t0, uint2 (&mw)[2][4]) {
    const ushort_t* mbase = maskF + (size_t)((t0 >> 6) * 64 + G) * 2048;
    #pragma unroll
    for (int a = 0; a < 2; ++a)
      #pragma unroll
      for (int g2 = 0; g2 < 4; ++g2)
        mw[a][g2] = *(const uint2*)(mbase + (size_t)(((a * 4 + g2) * 64) + l) * 4);
  };
  auto compute = [&](const ushort_t* ks, const ushort_t* vs, const uint2 (&mw)[2][4]) {
    // S^T = K * Q^T : 2 t-tiles x 4 k-steps
    f32x16 sc[2] = {};
    __builtin_amdgcn_s_setprio(1);
    #pragma unroll
    for (int s = 0; s < 4; ++s) {
      #pragma unroll
      for (int mt = 0; mt < 2; ++mt) {
        const int row = mt * 32 + q_l;
        const int col = (s * 16 + hh * 8) ^ ((q_l & 7) * 8);
        const bf16x8 kf = *(const bf16x8*)(ks + row * 64 + col);
        sc[mt] = __builtin_amdgcn_mfma_f32_32x32x16_bf16(kf, qf[s], sc[mt], 0, 0, 0);
      }
    }
    __builtin_amdgcn_s_setprio(0);

    // mask multiply (scale*log2e folded) + tree row-max (8 group maxes, depth-3)
    float gm[8];
    #pragma unroll
    for (int a = 0; a < 2; ++a) {
      #pragma unroll
      for (int g2 = 0; g2 < 4; ++g2) {
        const unsigned lo = mw[a][g2].x, hi = mw[a][g2].y;
        float v0 = sc[a][g2 * 4 + 0] * bf2f((ushort_t)lo);
        float v1 = sc[a][g2 * 4 + 1] * bf2f((ushort_t)(lo >> 16));
        float v2 = sc[a][g2 * 4 + 2] * bf2f((ushort_t)hi);
        float v3 = sc[a][g2 * 4 + 3] * bf2f((ushort_t)(hi >> 16));
        sc[a][g2 * 4 + 0] = v0; sc[a][g2 * 4 + 1] = v1;
        sc[a][g2 * 4 + 2] = v2; sc[a][g2 * 4 + 3] = v3;
        gm[a * 4 + g2] = fmaxf(fmaxf(v0, v1), fmaxf(v2, v3));
      }
    }
    const float x0 = fmaxf(gm[0], gm[1]), x1 = fmaxf(gm[2], gm[3]);
    const float x2 = fmaxf(gm[4], gm[5]), x3 = fmaxf(gm[6], gm[7]);
    float tmax = fmaxf(fmaxf(x0, x1), fmaxf(x2, x3));
    tmax = xhalf_max(tmax, hh);  // partner half holds other 32 t

    // defer-max online rescale (T13)
    if (!__all(tmax <= m_run + DEFER_THR)) {
      const float mnew = fmaxf(m_run, tmax);
      const float rf = fast_exp2(m_run - mnew);
      m_run = mnew;
      l_run *= rf;
      #pragma unroll
      for (int et = 0; et < 2; ++et)
        #pragma unroll
        for (int r = 0; r < 16; ++r) po[et][r] *= rf;
    }

    // P = exp2(s - m), 4-way interleaved row-sum, pack to bf16 words (T12)
    float ps[4] = {0.f, 0.f, 0.f, 0.f};
    unsigned pw[2][8];
    #pragma unroll
    for (int a = 0; a < 2; ++a)
      #pragma unroll
      for (int j = 0; j < 8; ++j) {
        const float p0 = fast_exp2(sc[a][2 * j] - m_run);
        const float p1 = fast_exp2(sc[a][2 * j + 1] - m_run);
        ps[a * 2 + (j & 1)] += p0 + p1;
        pw[a][j] = cvt_pk_bf16(p0, p1);
      }
    l_run += xhalf_sum((ps[0] + ps[1]) + (ps[2] + ps[3]), hh);

    // redistribute halves: build PV B-fragment word order
    #pragma unroll
    for (int a = 0; a < 2; ++a) {
      plane32_swap(pw[a][0], pw[a][2], hh);
      plane32_swap(pw[a][1], pw[a][3], hh);
      plane32_swap(pw[a][4], pw[a][6], hh);
      plane32_swap(pw[a][5], pw[a][7], hh);
    }

    // O^T += V^T * P
    __builtin_amdgcn_s_setprio(1);
    #pragma unroll
    for (int s = 0; s < 4; ++s) {
      union { unsigned u[4]; bf16x8 v; } pf;
      pf.u[0] = pw[s >> 1][(s & 1) * 4 + 0];
      pf.u[1] = pw[s >> 1][(s & 1) * 4 + 1];
      pf.u[2] = pw[s >> 1][(s & 1) * 4 + 2];
      pf.u[3] = pw[s >> 1][(s & 1) * 4 + 3];
      #pragma unroll
      for (int et = 0; et < 2; ++et) {
        const int row = et * 32 + q_l;
        const int col = (s * 16 + hh * 8) ^ ((q_l & 7) * 8);
        const bf16x8 vf = *(const bf16x8*)(vs + row * 64 + col);
        po[et] = __builtin_amdgcn_mfma_f32_32x32x16_bf16(vf, pf.v, po[et], 0, 0, 0);
      }
    }
    __builtin_amdgcn_s_setprio(0);
  };

  // prologue: stage tile 0, prefetch mask 0
  stage(0, Ks[0], Vs[0]);
  uint2 mwA[2][4], mwB[2][4];
  loadmask(0, mwA);

  // main loop: 2 tiles per iteration, named A/B mask regs (2-deep mask pipeline)
  for (int t0 = 0; t0 < 2048; t0 += 128) {
    __syncthreads();                       // buf0 staged; buf1 free
    stage(t0 + 64, Ks[1], Vs[1]);          // t0+64 <= 1984 always valid
    loadmask(t0 + 64, mwB);
    compute(Ks[0], Vs[0], mwA);
    __syncthreads();                       // buf1 staged; buf0 free
    if (t0 + 128 < 2048) {
      stage(t0 + 128, Ks[0], Vs[0]);
      loadmask(t0 + 128, mwA);
    }
    compute(Ks[1], Vs[1], mwB);
  }

  // epilogue: normalize, transpose O^T->O via LDS (reuse Ks region), coalesced store
  const float invl = 1.0f / l_run;
  __syncthreads();
  ushort_t* ow = &Ks[0][0] + w * 2048;  // 4KB per wave (32q x 64e)
  #pragma unroll
  for (int et = 0; et < 2; ++et)
    #pragma unroll
    for (int r = 0; r < 16; ++r) {
      const int e = et * 32 + (r & 3) + 8 * (r >> 2) + 4 * hh;
      const int ba = (q_l * 128 + e * 2) ^ ((q_l & 7) << 4);
      *(ushort_t*)((char*)ow + ba) = f2bf(po[et][r] * invl);
    }
  __syncthreads();
  {
    union { ushort_t hs[32]; uint2 u2[8]; uint4 u4[4]; } ov;
    const int ebase = hh * 32;
    #pragma unroll
    for (int c = 0; c < 8; ++c) {
      const int e0 = ebase + c * 4;
      const int ba = (q_l * 128 + e0 * 2) ^ ((q_l & 7) << 4);
      ov.u2[c] = *(const uint2*)((const char*)ow + ba);
    }
    ushort_t* dst = concat + ((size_t)(b * 2048 + qbase + q_l)) * 1024 + h * 64 + ebase;
    #pragma unroll
    for (int c2 = 0; c2 < 4; ++c2)
      ((uint4*)dst)[c2] = ov.u4[c2];
  }
}

extern "C" void kernel_launch(void* const* d_in, const int* in_sizes, int n_in,
                              void* d_out, int out_size, void* d_ws, size_t ws_size,
                              hipStream_t stream) {
  const float* q    = (const float*)d_in[0];
  const float* k    = (const float*)d_in[1];
  const float* v    = (const float*)d_in[2];
  const float* mask = (const float*)d_in[3];
  const float* Wq   = (const float*)d_in[4];
  const float* bq   = (const float*)d_in[5];
  const float* Wk   = (const float*)d_in[6];
  const float* bk   = (const float*)d_in[7];
  const float* Wv   = (const float*)d_in[8];
  const float* bv   = (const float*)d_in[9];
  const float* Wo   = (const float*)d_in[10];
  const float* bo   = (const float*)d_in[11];

  const size_t SZ8M = (size_t)4096 * 1024 * 2;   // 8 MiB buffers (bf16)
  const size_t SZ2M = (size_t)1024 * 1024 * 2;   // 2 MiB weight buffers
  if (ws_size < 7 * SZ8M + 4 * SZ2M) return;     // need 64 MiB scratch

  char* p = (char*)d_ws;
  ushort_t* qb    = (ushort_t*)p; p += SZ8M;     // reused as `concat` after qkv_gemm
  ushort_t* kb    = (ushort_t*)p; p += SZ8M;
  ushort_t* vb    = (ushort_t*)p; p += SZ8M;
  ushort_t* maskb = (ushort_t*)p; p += SZ8M;     // fragment-packed mask
  ushort_t* Qo    = (ushort_t*)p; p += SZ8M;
  ushort_t* Ko    = (ushort_t*)p; p += SZ8M;
  ushort_t* Vto   = (ushort_t*)p; p += SZ8M;
  ushort_t* Wtq   = (ushort_t*)p; p += SZ2M;
  ushort_t* Wtk   = (ushort_t*)p; p += SZ2M;
  ushort_t* Wtv   = (ushort_t*)p; p += SZ2M;
  ushort_t* Wot   = (ushort_t*)p; p += SZ2M;
  ushort_t* concat = qb;

  cvt3_f32_bf16<<<dim3(2048, 3), dim3(256), 0, stream>>>(q, k, v, qb, kb, vb);
  mask_pack<<<dim3(2048), dim3(256), 0, stream>>>(mask, maskb);
  transpose_cvt3<<<dim3(1, 16, 48), dim3(256), 0, stream>>>(Wq, Wk, Wv, Wtq, Wtk, Wtv);
  transpose_cvt<<<dim3(16, 16), dim3(256), 0, stream>>>(Wo, Wot, 1024, 1024);
  qkv_gemm<<<dim3(32, 8, 3), dim3(256), 0, stream>>>(qb, kb, vb, Wtq, Wtk, Wtv, bq, bk, bv, Qo, Ko, Vto);
  flash_attn<<<dim3(32, 32), dim3(128), 0, stream>>>(Qo, Ko, Vto, maskb, concat);
  out_gemm<<<dim3(64, 8), dim3(256), 0, stream>>>(concat, Wot, bo, (float*)d_out);
}

// Round 8
// 135.017 us; speedup vs baseline: 1.5592x; 1.0505x over previous
//
#include <hip/hip_runtime.h>
#include <stdint.h>

// MultiHeadAttention: B=2, S=2048, H=16, Dh=64, Dm=1024
// Pipeline: prep_all (cvt+mask_pack+W transposes) -> QKV GEMM -> flash attn (defer-max, R4-verbatim) -> out GEMM
#define DM 1024
#define HNUM 16
#define DH 64
#define BB 2
#define SSEQ 2048

typedef unsigned short ushort_t;
typedef __attribute__((ext_vector_type(8))) short bf16x8;
typedef __attribute__((ext_vector_type(4))) float f32x4;
typedef __attribute__((ext_vector_type(16))) float f32x16;

// 0.125 * log2(e): folded into packed mask so softmax runs in exp2 domain
#define SCALE2 0.18033688011112042f
#define DEFER_THR 11.0f   // defer-max threshold (exp2 domain); P bounded by 2^11

// ---- bf16 helpers (bit-level) ----
__device__ __forceinline__ ushort_t f2bf(float f) {
  unsigned u = __builtin_bit_cast(unsigned, f);
  u += 0x7FFFu + ((u >> 16) & 1u);  // RNE
  return (ushort_t)(u >> 16);
}
__device__ __forceinline__ float bf2f(ushort_t h) {
  return __builtin_bit_cast(float, (unsigned)h << 16);
}
__device__ __forceinline__ float fast_exp2(float x) {
#if __has_builtin(__builtin_amdgcn_exp2f)
  return __builtin_amdgcn_exp2f(x);
#else
  return exp2f(x);
#endif
}
// packed RNE f32x2 -> bf16x2 (one instruction)
__device__ __forceinline__ unsigned cvt_pk_bf16(float lo, float hi) {
  unsigned r;
  asm("v_cvt_pk_bf16_f32 %0, %1, %2" : "=v"(r) : "v"(lo), "v"(hi));
  return r;
}
// {a',b'} halves swap (T12 recipe)
__device__ __forceinline__ void plane32_swap(unsigned& a, unsigned& b, int hh) {
#if __has_builtin(__builtin_amdgcn_permlane32_swap)
  typedef int v2i __attribute__((ext_vector_type(2)));
  v2i r = __builtin_amdgcn_permlane32_swap((int)a, (int)b, 0, 0);
  a = (unsigned)r.x; b = (unsigned)r.y;
#else
  unsigned sa = (unsigned)__shfl_xor((int)a, 32);
  unsigned sb = (unsigned)__shfl_xor((int)b, 32);
  unsigned na = hh ? sb : a;
  unsigned nb = hh ? b : sa;
  a = na; b = nb;
#endif
}

// ---- async global->LDS, 16B per lane; dest = wave-uniform base + lane*16 ----
typedef const __attribute__((address_space(1))) unsigned int* gas_ptr;
typedef __attribute__((address_space(3))) unsigned int* las_ptr;
__device__ __forceinline__ void gload_lds16(const void* g, void* l) {
  __builtin_amdgcn_global_load_lds((gas_ptr)(uintptr_t)g, (las_ptr)(uintptr_t)l, 16, 0, 0);
}

// ---- prep_all: cvt q/k/v, mask pack, W_q/k/v transpose, W_o transpose in ONE launch ----
// block ranges: [0,6144) cvt3 | [6144,8192) mask | [8192,8960) Wqkv | [8960,9216) Wo
__global__ void prep_all(const float* __restrict__ q, const float* __restrict__ k,
                         const float* __restrict__ v, const float* __restrict__ mask,
                         const float* __restrict__ Wq, const float* __restrict__ Wk,
                         const float* __restrict__ Wv, const float* __restrict__ Wo,
                         ushort_t* __restrict__ qd, ushort_t* __restrict__ kd,
                         ushort_t* __restrict__ vd, ushort_t* __restrict__ maskd,
                         ushort_t* __restrict__ dq, ushort_t* __restrict__ dk,
                         ushort_t* __restrict__ dv, ushort_t* __restrict__ dWo) {
  __shared__ ushort_t T[64][65];
  const int bx = blockIdx.x, tid = threadIdx.x;
  if (bx < 6144) {
    // fp32 -> bf16 bulk convert (8 elems/thread)
    const int z = bx >> 11, bi = bx & 2047;
    const float* src = z == 0 ? q : (z == 1 ? k : v);
    ushort_t* dst    = z == 0 ? qd : (z == 1 ? kd : vd);
    const int idx = bi * 256 + tid;
    const float4* s4 = (const float4*)src;
    float4 a = s4[idx * 2], c = s4[idx * 2 + 1];
    union { ushort_t h[8]; uint4 u; } o;
    o.h[0] = f2bf(a.x); o.h[1] = f2bf(a.y); o.h[2] = f2bf(a.z); o.h[3] = f2bf(a.w);
    o.h[4] = f2bf(c.x); o.h[5] = f2bf(c.y); o.h[6] = f2bf(c.z); o.h[7] = f2bf(c.w);
    ((uint4*)dst)[idx] = o.u;
  } else if (bx < 8192) {
    // mask pack for swapped-QK^T fragment layout
    // word wd = (a*4+g2)*64 + l ; elem j: (qr = G*32+(l&31), t = T*64+32a+8g2+4*(l>>5)+j)
    const int TG = bx - 6144;
    const int Tt = TG >> 6, G = TG & 63;
    #pragma unroll
    for (int i = 0; i < 2; ++i) {
      const int wd = tid * 2 + i;        // [0,512)
      const int l = wd & 63, g2 = (wd >> 6) & 3, a = wd >> 8;
      const int qr = G * 32 + (l & 31);
      const int t = Tt * 64 + a * 32 + g2 * 8 + (l >> 5) * 4;
      float4 mv = *(const float4*)(mask + (size_t)qr * 2048 + t);
      union { ushort_t h4[4]; uint2 u; } pk;
      pk.h4[0] = f2bf(mv.x * SCALE2); pk.h4[1] = f2bf(mv.y * SCALE2);
      pk.h4[2] = f2bf(mv.z * SCALE2); pk.h4[3] = f2bf(mv.w * SCALE2);
      *(uint2*)(maskd + (size_t)TG * 2048 + (size_t)wd * 4) = pk.u;
    }
  } else if (bx < 8960) {
    // W_{q,k,v} transpose: [16][1024][64] -> per-head [64][1024]
    const int id = bx - 8192;
    const int zz = id >> 4, yy = id & 15;
    const int mat = zz >> 4, g = zz & 15;
    const float* src = (mat == 0 ? Wq : (mat == 1 ? Wk : Wv)) + (size_t)g * 1024 * 64;
    ushort_t* dst    = (mat == 0 ? dq : (mat == 1 ? dk : dv)) + (size_t)g * 1024 * 64;
    const int r0 = yy * 64;
    #pragma unroll
    for (int i = 0; i < 16; ++i) {
      int idx = i * 256 + tid;
      int r = idx >> 6, c = idx & 63;
      T[r][c] = f2bf(src[(size_t)(r0 + r) * 64 + c]);
    }
    __syncthreads();
    #pragma unroll
    for (int i = 0; i < 16; ++i) {
      int idx = i * 256 + tid;
      int cc = idx >> 6, rr = idx & 63;
      dst[(size_t)cc * 1024 + r0 + rr] = T[rr][cc];
    }
  } else {
    // W_o transpose: [1024][1024] -> [1024][1024]^T
    const int id = bx - 8960;
    const int c0 = (id & 15) * 64, r0 = (id >> 4) * 64;
    #pragma unroll
    for (int i = 0; i < 16; ++i) {
      int idx = i * 256 + tid;
      int r = idx >> 6, c = idx & 63;
      T[r][c] = f2bf(Wo[(size_t)(r0 + r) * 1024 + c0 + c]);
    }
    __syncthreads();
    #pragma unroll
    for (int i = 0; i < 16; ++i) {
      int idx = i * 256 + tid;
      int cc = idx >> 6, rr = idx & 63;
      dWo[(size_t)(c0 + cc) * 1024 + r0 + rr] = T[rr][cc];
    }
  }
}

// ---- 128x128-tile GEMM mainloop: C[128,128] = A[128rows,K=1024] * Bm^T, Bm is [n][k] ----
__device__ __forceinline__ void gemm_mainloop_128(const ushort_t* __restrict__ A,
                                                  const ushort_t* __restrict__ Bm,
                                                  f32x4 (&acc)[4][4], int m0, int n0, int l, int w) {
  __shared__ ushort_t As[128 * 64];
  __shared__ ushort_t Bs[128 * 64];
  const int wr = w >> 1, wc = w & 1;
  for (int ks = 0; ks < 16; ++ks) {
    const int k0 = ks * 64;
    #pragma unroll
    for (int it = 0; it < 4; ++it) {
      const int chunk = it * 4 + w;
      const int row = chunk * 8 + (l >> 3);
      const int kc = ((l & 7) * 8) ^ ((row & 7) * 8);  // pre-swizzled source
      gload_lds16(A + (size_t)(m0 + row) * 1024 + k0 + kc, (char*)As + chunk * 1024);
      gload_lds16(Bm + (size_t)(n0 + row) * 1024 + k0 + kc, (char*)Bs + chunk * 1024);
    }
    __syncthreads();
    #pragma unroll
    for (int kk = 0; kk < 2; ++kk) {
      bf16x8 af[4], bfr[4];
      #pragma unroll
      for (int mi = 0; mi < 4; ++mi) {
        const int row = wr * 64 + mi * 16 + (l & 15);
        const int kc = (kk * 32 + (l >> 4) * 8) ^ ((row & 7) * 8);
        af[mi] = *(const bf16x8*)(As + row * 64 + kc);
      }
      #pragma unroll
      for (int ni = 0; ni < 4; ++ni) {
        const int row = wc * 64 + ni * 16 + (l & 15);
        const int kc = (kk * 32 + (l >> 4) * 8) ^ ((row & 7) * 8);
        bfr[ni] = *(const bf16x8*)(Bs + row * 64 + kc);
      }
      #pragma unroll
      for (int mi = 0; mi < 4; ++mi)
        #pragma unroll
        for (int ni = 0; ni < 4; ++ni)
          acc[mi][ni] = __builtin_amdgcn_mfma_f32_16x16x32_bf16(af[mi], bfr[ni], acc[mi][ni], 0, 0, 0);
    }
    __syncthreads();
  }
}

// ---- QKV projection: z=0 Q, z=1 K (layout [b][h][s][e]), z=2 V (transposed [b][h][e][s]) ----
__global__ __launch_bounds__(256, 2) void qkv_gemm(
    const ushort_t* __restrict__ qb, const ushort_t* __restrict__ kb, const ushort_t* __restrict__ vb,
    const ushort_t* __restrict__ Wtq, const ushort_t* __restrict__ Wtk, const ushort_t* __restrict__ Wtv,
    const float* __restrict__ bq, const float* __restrict__ bk, const float* __restrict__ bv,
    ushort_t* __restrict__ Qo, ushort_t* __restrict__ Ko, ushort_t* __restrict__ Vto) {
  const int z = blockIdx.z;
  const ushort_t* A  = z == 0 ? qb : (z == 1 ? kb : vb);
  const ushort_t* Bm = z == 0 ? Wtq : (z == 1 ? Wtk : Wtv);
  const float* bias  = z == 0 ? bq : (z == 1 ? bk : bv);
  ushort_t* out      = z == 0 ? Qo : (z == 1 ? Ko : Vto);
  const int m0 = blockIdx.x * 128, n0 = blockIdx.y * 128;
  const int tid = threadIdx.x, l = tid & 63, w = tid >> 6;
  f32x4 acc[4][4] = {};
  gemm_mainloop_128(A, Bm, acc, m0, n0, l, w);
  const int wr = w >> 1, wc = w & 1;
  #pragma unroll
  for (int mi = 0; mi < 4; ++mi) {
    #pragma unroll
    for (int ni = 0; ni < 4; ++ni) {
      const int n = n0 + wc * 64 + ni * 16 + (l & 15);
      const float bb = bias[n];
      const int mbase = m0 + wr * 64 + mi * 16 + ((l >> 4) << 2);
      if (z < 2) {
        #pragma unroll
        for (int i = 0; i < 4; ++i) {
          const int m = mbase + i;
          const size_t o = (((size_t)((m >> 11) * 16 + (n >> 6))) * 2048 + (m & 2047)) * 64 + (n & 63);
          out[o] = f2bf(acc[mi][ni][i] + bb);
        }
      } else {
        union { ushort_t h[4]; uint2 u2; } pk;
        #pragma unroll
        for (int i = 0; i < 4; ++i) pk.h[i] = f2bf(acc[mi][ni][i] + bb);
        const size_t o = (((size_t)((mbase >> 11) * 16 + (n >> 6))) * 64 + (n & 63)) * 2048 + (mbase & 2047);
        *(uint2*)(out + o) = pk.u2;
      }
    }
  }
}

// ---- output projection: 64x128 tiles (512 blocks = 2/CU), d_out fp32 [4096][1024] ----
__global__ __launch_bounds__(256, 2) void out_gemm(const ushort_t* __restrict__ A,
                                                   const ushort_t* __restrict__ Bm,
                                                   const float* __restrict__ bias,
                                                   float* __restrict__ out) {
  __shared__ ushort_t As[64 * 64];
  __shared__ ushort_t Bs[128 * 64];
  const int m0 = blockIdx.x * 64, n0 = blockIdx.y * 128;
  const int tid = threadIdx.x, l = tid & 63, w = tid >> 6;
  const int wr = w >> 1, wc = w & 1;
  f32x4 acc[2][4] = {};
  for (int ks = 0; ks < 16; ++ks) {
    const int k0 = ks * 64;
    #pragma unroll
    for (int it = 0; it < 6; ++it) {
      const int chunk = it * 4 + w;     // 0..23: 0-7 -> As, 8-23 -> Bs
      if (chunk < 8) {
        const int row = chunk * 8 + (l >> 3);
        const int kc = ((l & 7) * 8) ^ ((row & 7) * 8);
        gload_lds16(A + (size_t)(m0 + row) * 1024 + k0 + kc, (char*)As + chunk * 1024);
      } else {
        const int c2 = chunk - 8;
        const int row = c2 * 8 + (l >> 3);
        const int kc = ((l & 7) * 8) ^ ((row & 7) * 8);
        gload_lds16(Bm + (size_t)(n0 + row) * 1024 + k0 + kc, (char*)Bs + c2 * 1024);
      }
    }
    __syncthreads();
    #pragma unroll
    for (int kk = 0; kk < 2; ++kk) {
      bf16x8 af[2], bfr[4];
      #pragma unroll
      for (int mi = 0; mi < 2; ++mi) {
        const int row = wr * 32 + mi * 16 + (l & 15);
        const int kc = (kk * 32 + (l >> 4) * 8) ^ ((row & 7) * 8);
        af[mi] = *(const bf16x8*)(As + row * 64 + kc);
      }
      #pragma unroll
      for (int ni = 0; ni < 4; ++ni) {
        const int row = wc * 64 + ni * 16 + (l & 15);
        const int kc = (kk * 32 + (l >> 4) * 8) ^ ((row & 7) * 8);
        bfr[ni] = *(const bf16x8*)(Bs + row * 64 + kc);
      }
      #pragma unroll
      for (int mi = 0; mi < 2; ++mi)
        #pragma unroll
        for (int ni = 0; ni < 4; ++ni)
          acc[mi][ni] = __builtin_amdgcn_mfma_f32_16x16x32_bf16(af[mi], bfr[ni], acc[mi][ni], 0, 0, 0);
    }
    __syncthreads();
  }
  #pragma unroll
  for (int mi = 0; mi < 2; ++mi) {
    #pragma unroll
    for (int ni = 0; ni < 4; ++ni) {
      const int n = n0 + wc * 64 + ni * 16 + (l & 15);
      const float bb = bias[n];
      const int mbase = m0 + wr * 32 + mi * 16 + ((l >> 4) << 2);
      #pragma unroll
      for (int i = 0; i < 4; ++i)
        out[(size_t)(mbase + i) * 1024 + n] = acc[mi][ni][i] + bb;
    }
  }
}

// ---- flash attention (R4-verbatim): swapped QK^T (32x32 MFMA), in-register softmax, defer-max ----
// Block: 4 waves x 32 q-rows = 128 q-rows; KVBLK=64 double-buffered.
__device__ __forceinline__ void stage_kv(const ushort_t* __restrict__ Kb, const ushort_t* __restrict__ Vb,
                                         int t0, ushort_t* ks, ushort_t* vs, int l, int w) {
  #pragma unroll
  for (int half = 0; half < 2; ++half) {
    const int c = half * 4 + w;
    const int r1 = c * 8 + (l >> 3);
    const int cc = ((l & 7) * 8) ^ ((r1 & 7) * 8);  // pre-swizzled source col
    gload_lds16(Kb + (size_t)(t0 + r1) * 64 + cc, (char*)ks + c * 1024);
    gload_lds16(Vb + (size_t)r1 * 2048 + t0 + cc, (char*)vs + c * 1024);
  }
}

__global__ __launch_bounds__(256, 2) void flash_attn(const ushort_t* __restrict__ Q,
                                                     const ushort_t* __restrict__ K,
                                                     const ushort_t* __restrict__ Vt,
                                                     const ushort_t* __restrict__ maskF,
                                                     ushort_t* __restrict__ concat) {
  const int bh = blockIdx.y, b = bh >> 4, h = bh & 15;
  const int tid = threadIdx.x, l = tid & 63, w = tid >> 6;
  const int hh = l >> 5, q_l = l & 31;
  __shared__ ushort_t Ks[2][64 * 64];
  __shared__ ushort_t Vs[2][64 * 64];
  const ushort_t* Qb = Q + (size_t)bh * 2048 * 64;
  const ushort_t* Kb = K + (size_t)bh * 2048 * 64;
  const ushort_t* Vb = Vt + (size_t)bh * 64 * 2048;
  const int qbase = blockIdx.x * 128 + w * 32;
  const int G = qbase >> 5;

  // Q as MFMA-B fragments: lane holds col q=l&31, k = s*16 + hh*8 + j
  bf16x8 qf[4];
  #pragma unroll
  for (int s = 0; s < 4; ++s)
    qf[s] = *(const bf16x8*)(Qb + (size_t)(qbase + q_l) * 64 + s * 16 + hh * 8);

  float m_run = -1e30f, l_run = 0.f;
  f32x16 po[2] = {};  // O^T accumulators (e-tiles), col q = l&31

  stage_kv(Kb, Vb, 0, Ks[0], Vs[0], l, w);
  int cur = 0;

  for (int t0 = 0; t0 < 2048; t0 += 64) {
    __syncthreads();  // cur staged (vmcnt drain), prev buffer free
    if (t0 + 64 < 2048) stage_kv(Kb, Vb, t0 + 64, Ks[cur ^ 1], Vs[cur ^ 1], l, w);

    // packed mask: 8 coalesced uint2 loads
    const ushort_t* mbase = maskF + (size_t)((t0 >> 6) * 64 + G) * 2048;
    uint2 mw[2][4];
    #pragma unroll
    for (int a = 0; a < 2; ++a)
      #pragma unroll
      for (int g2 = 0; g2 < 4; ++g2)
        mw[a][g2] = *(const uint2*)(mbase + (size_t)(((a * 4 + g2) * 64) + l) * 4);

    // S^T = K * Q^T : 2 t-tiles x 4 k-steps
    f32x16 sc[2] = {};
    #pragma unroll
    for (int s = 0; s < 4; ++s) {
      #pragma unroll
      for (int mt = 0; mt < 2; ++mt) {
        const int row = mt * 32 + q_l;
        const int col = (s * 16 + hh * 8) ^ ((q_l & 7) * 8);
        const bf16x8 kf = *(const bf16x8*)(Ks[cur] + row * 64 + col);
        sc[mt] = __builtin_amdgcn_mfma_f32_32x32x16_bf16(kf, qf[s], sc[mt], 0, 0, 0);
      }
    }

    // mask multiply (scale*log2e folded) + in-register row max
    float tmax = -1e30f;
    #pragma unroll
    for (int a = 0; a < 2; ++a) {
      #pragma unroll
      for (int g2 = 0; g2 < 4; ++g2) {
        const unsigned lo = mw[a][g2].x, hi = mw[a][g2].y;
        float v0 = sc[a][g2 * 4 + 0] * bf2f((ushort_t)lo);
        float v1 = sc[a][g2 * 4 + 1] * bf2f((ushort_t)(lo >> 16));
        float v2 = sc[a][g2 * 4 + 2] * bf2f((ushort_t)hi);
        float v3 = sc[a][g2 * 4 + 3] * bf2f((ushort_t)(hi >> 16));
        sc[a][g2 * 4 + 0] = v0; sc[a][g2 * 4 + 1] = v1;
        sc[a][g2 * 4 + 2] = v2; sc[a][g2 * 4 + 3] = v3;
        tmax = fmaxf(tmax, fmaxf(fmaxf(v0, v1), fmaxf(v2, v3)));
      }
    }
    tmax = fmaxf(tmax, __shfl_xor(tmax, 32));  // partner half holds other 32 t

    // defer-max online rescale (T13): skip O-rescale while growth <= THR
    if (!__all(tmax <= m_run + DEFER_THR)) {
      const float mnew = fmaxf(m_run, tmax);
      const float rf = fast_exp2(m_run - mnew);
      m_run = mnew;
      l_run *= rf;
      #pragma unroll
      for (int et = 0; et < 2; ++et)
        #pragma unroll
        for (int r = 0; r < 16; ++r) po[et][r] *= rf;
    }

    // P = exp2(s - m), row-sum, pack to bf16 words (T12)
    float psum = 0.f;
    unsigned pw[2][8];
    #pragma unroll
    for (int a = 0; a < 2; ++a)
      #pragma unroll
      for (int j = 0; j < 8; ++j) {
        const float p0 = fast_exp2(sc[a][2 * j] - m_run);
        const float p1 = fast_exp2(sc[a][2 * j + 1] - m_run);
        psum += p0 + p1;
        pw[a][j] = cvt_pk_bf16(p0, p1);
      }
    psum += __shfl_xor(psum, 32);
    l_run += psum;

    // redistribute halves: build PV B-fragment word order
    #pragma unroll
    for (int a = 0; a < 2; ++a) {
      plane32_swap(pw[a][0], pw[a][2], hh);
      plane32_swap(pw[a][1], pw[a][3], hh);
      plane32_swap(pw[a][4], pw[a][6], hh);
      plane32_swap(pw[a][5], pw[a][7], hh);
    }

    // O^T += V^T * P : A = V^T tile rows e, B = P
    #pragma unroll
    for (int s = 0; s < 4; ++s) {
      union { unsigned u[4]; bf16x8 v; } pf;
      pf.u[0] = pw[s >> 1][(s & 1) * 4 + 0];
      pf.u[1] = pw[s >> 1][(s & 1) * 4 + 1];
      pf.u[2] = pw[s >> 1][(s & 1) * 4 + 2];
      pf.u[3] = pw[s >> 1][(s & 1) * 4 + 3];
      #pragma unroll
      for (int et = 0; et < 2; ++et) {
        const int row = et * 32 + q_l;
        const int col = (s * 16 + hh * 8) ^ ((q_l & 7) * 8);
        const bf16x8 vf = *(const bf16x8*)(Vs[cur] + row * 64 + col);
        po[et] = __builtin_amdgcn_mfma_f32_32x32x16_bf16(vf, pf.v, po[et], 0, 0, 0);
      }
    }
    cur ^= 1;
  }

  // epilogue: normalize, transpose O^T->O via LDS (reuse Ks region), coalesced store
  const float invl = 1.0f / l_run;
  __syncthreads();
  ushort_t* ow = &Ks[0][0] + w * 2048;  // 4KB per wave (32q x 64e)
  #pragma unroll
  for (int et = 0; et < 2; ++et)
    #pragma unroll
    for (int r = 0; r < 16; ++r) {
      const int e = et * 32 + (r & 3) + 8 * (r >> 2) + 4 * hh;
      const int ba = (q_l * 128 + e * 2) ^ ((q_l & 7) << 4);
      *(ushort_t*)((char*)ow + ba) = f2bf(po[et][r] * invl);
    }
  __syncthreads();
  {
    union { ushort_t hs[32]; uint2 u2[8]; uint4 u4[4]; } ov;
    const int ebase = hh * 32;
    #pragma unroll
    for (int c = 0; c < 8; ++c) {
      const int e0 = ebase + c * 4;
      const int ba = (q_l * 128 + e0 * 2) ^ ((q_l & 7) << 4);
      ov.u2[c] = *(const uint2*)((const char*)ow + ba);
    }
    ushort_t* dst = concat + ((size_t)(b * 2048 + qbase + q_l)) * 1024 + h * 64 + ebase;
    #pragma unroll
    for (int c2 = 0; c2 < 4; ++c2)
      ((uint4*)dst)[c2] = ov.u4[c2];
  }
}

extern "C" void kernel_launch(void* const* d_in, const int* in_sizes, int n_in,
                              void* d_out, int out_size, void* d_ws, size_t ws_size,
                              hipStream_t stream) {
  const float* q    = (const float*)d_in[0];
  const float* k    = (const float*)d_in[1];
  const float* v    = (const float*)d_in[2];
  const float* mask = (const float*)d_in[3];
  const float* Wq   = (const float*)d_in[4];
  const float* bq   = (const float*)d_in[5];
  const float* Wk   = (const float*)d_in[6];
  const float* bk   = (const float*)d_in[7];
  const float* Wv   = (const float*)d_in[8];
  const float* bv   = (const float*)d_in[9];
  const float* Wo   = (const float*)d_in[10];
  const float* bo   = (const float*)d_in[11];

  const size_t SZ8M = (size_t)4096 * 1024 * 2;   // 8 MiB buffers (bf16)
  const size_t SZ2M = (size_t)1024 * 1024 * 2;   // 2 MiB weight buffers
  if (ws_size < 7 * SZ8M + 4 * SZ2M) return;     // need 64 MiB scratch

  char* p = (char*)d_ws;
  ushort_t* qb    = (ushort_t*)p; p += SZ8M;     // reused as `concat` after qkv_gemm
  ushort_t* kb    = (ushort_t*)p; p += SZ8M;
  ushort_t* vb    = (ushort_t*)p; p += SZ8M;
  ushort_t* maskb = (ushort_t*)p; p += SZ8M;     // fragment-packed mask
  ushort_t* Qo    = (ushort_t*)p; p += SZ8M;
  ushort_t* Ko    = (ushort_t*)p; p += SZ8M;
  ushort_t* Vto   = (ushort_t*)p; p += SZ8M;
  ushort_t* Wtq   = (ushort_t*)p; p += SZ2M;
  ushort_t* Wtk   = (ushort_t*)p; p += SZ2M;
  ushort_t* Wtv   = (ushort_t*)p; p += SZ2M;
  ushort_t* Wot   = (ushort_t*)p; p += SZ2M;
  ushort_t* concat = qb;

  prep_all<<<dim3(9216), dim3(256), 0, stream>>>(q, k, v, mask, Wq, Wk, Wv, Wo,
                                                 qb, kb, vb, maskb, Wtq, Wtk, Wtv, Wot);
  qkv_gemm<<<dim3(32, 8, 3), dim3(256), 0, stream>>>(qb, kb, vb, Wtq, Wtk, Wtv, bq, bk, bv, Qo, Ko, Vto);
  flash_attn<<<dim3(16, 32), dim3(256), 0, stream>>>(Qo, Ko, Vto, maskb, concat);
  out_gemm<<<dim3(64, 8), dim3(256), 0, stream>>>(concat, Wot, bo, (float*)d_out);
}